// Round 6
// baseline (472.366 us; speedup 1.0000x reference)
//
#include <hip/hip_runtime.h>
#include <hip/hip_bf16.h>
#include <math.h>

typedef __bf16 bf16;
typedef __attribute__((ext_vector_type(8))) __bf16 bf16x8;
typedef __attribute__((ext_vector_type(4))) __bf16 bf16x4;
typedef __attribute__((ext_vector_type(2))) __bf16 bf16x2;
typedef __attribute__((ext_vector_type(4))) float f32x4;
typedef __attribute__((ext_vector_type(4))) short short4v;

#define HDIM 1024
#define NHEAD 16
#define HD 64
#define FFDIM 4096
#define BATCH 2
#define SEQ 2048
#define M_TOK 4096  // BATCH*SEQ
#define NSPLIT 4
#define PSTRIDE ((size_t)M_TOK * HDIM)  // elements between split-K partials

static __device__ __forceinline__ void async_load16(const bf16* g, bf16* l) {
  __builtin_amdgcn_global_load_lds(
      (const __attribute__((address_space(1))) void*)g,
      (__attribute__((address_space(3))) void*)l, 16, 0, 0);
}

// 16x16x16 bf16 MFMA wrapper (attn uses it). Host pass has no amdgcn builtins.
static __device__ __forceinline__ f32x4 mfma16_bf16(bf16x4 a, bf16x4 b, f32x4 c) {
#if defined(__HIP_DEVICE_COMPILE__)
#if __has_builtin(__builtin_amdgcn_mfma_f32_16x16x16bf16_1k)
  return __builtin_amdgcn_mfma_f32_16x16x16bf16_1k(
      __builtin_bit_cast(short4v, a), __builtin_bit_cast(short4v, b), c, 0, 0, 0);
#else
  return __builtin_amdgcn_mfma_f32_16x16x16_bf16(a, b, c, 0, 0, 0);
#endif
#else
  return c;  // host pass: never executed
#endif
}

// ---------------------------------------------------------------- prep: all transposes + x cast
// z 0..3: Wq/Wk/Wv/Wo -> QKVT; z 4..7: W1 -> W1T; z 8..11: W2 -> W2T; z 12: cast x
__global__ __launch_bounds__(256)
void prep_kernel(const float* __restrict__ x,
                 const float* __restrict__ Wq, const float* __restrict__ Wk,
                 const float* __restrict__ Wv, const float* __restrict__ Wo,
                 const float* __restrict__ W1, const float* __restrict__ W2,
                 bf16* __restrict__ Xb, bf16* __restrict__ QKVT,
                 bf16* __restrict__ W1T, bf16* __restrict__ W2T)
{
  const int z = blockIdx.z;
  const int t = threadIdx.x;
  if (z == 12) {
    const size_t base = ((size_t)(blockIdx.y * 32 + blockIdx.x)) * 4096;
#pragma unroll
    for (int j = 0; j < 4; ++j) {
      const size_t i = base + j * 1024 + t * 4;
      f32x4 v = *(const f32x4*)(x + i);
      bf16x4 o;
#pragma unroll
      for (int k = 0; k < 4; ++k) o[k] = (bf16)v[k];
      *(bf16x4*)(Xb + i) = o;
    }
    return;
  }
  const float* ps; bf16* pd; int sld, dld;
  if (z < 4) {
    ps = (z == 0) ? Wq : (z == 1) ? Wk : (z == 2) ? Wv : Wo;
    pd = QKVT + (size_t)z * HDIM * HDIM; sld = 1024; dld = 1024;
  } else if (z < 8) {
    const int c = z - 4;
    ps = W1 + c * 1024; sld = 4096;
    pd = W1T + (size_t)c * 1024 * 1024; dld = 1024;
  } else {
    const int c = z - 8;
    ps = W2 + (size_t)c * 1024 * 1024; sld = 1024;
    pd = W2T + c * 1024; dld = 4096;
  }
  __shared__ float tile[32][33];
  const int tx = t & 31, ty = t >> 5;
  const int c0 = blockIdx.x * 32, r0 = blockIdx.y * 32;
#pragma unroll
  for (int i = 0; i < 32; i += 8)
    tile[ty + i][tx] = ps[(size_t)(r0 + ty + i) * sld + c0 + tx];
  __syncthreads();
  const int rr0 = (t & 15) * 2;
  const int ccb = t >> 4;  // 0..15
#pragma unroll
  for (int i = 0; i < 2; ++i) {
    const int cc = ccb + 16 * i;
    bf16x2 v = {(bf16)tile[rr0][cc], (bf16)tile[rr0 + 1][cc]};
    *(bf16x2*)(pd + (size_t)(c0 + cc) * dld + r0 + rr0) = v;
  }
}

// ---------------------------------------------------------------- GEMM  C = A @ Bt^T (+ bias)
// 128x128 tile, 4 waves (2x2 of 64x64), 2-barrier loop, LDS-bounce epilogue,
// XCD swizzle.
// Round-6: B no longer staged through LDS. B operands are 2-8MB L2/L3-
// resident weights; staging them cost 8 ds_read_b128 + 4 global_load_lds
// per wave per K-step and saturated the LDS pipe (~206 B/cyc demand vs 128
// peak at 4 blocks/CU). Now each lane loads its B fragment directly:
//   bv[ks][nt] = Bt[(bn+wn+nt*16+lm)*ldk + k0+ks*32+qd*8 .. +8]
// (identical elements the un-swizzled LDS read produced; a wave reads 16
// full 64B lines per load -> bandwidth-equivalent to coalesced). Loads
// issue BEFORE the barrier, so the existing vmcnt(0)-at-barrier drain
// (already required for A's global_load_lds) hides their latency. A stays
// LDS-staged (larger operand, reused across wave pairs).
// EPI: 1 = bf16 partial (no bias, out + z*M*N), 2 = bias+gelu(A&S erf)->bf16,
//      3 = QKV fused epilogue (V stored transposed -> Vt[d][s])
template<int EPI>
__global__ __launch_bounds__(256)
void gemm_bt(const bf16* __restrict__ A, const bf16* __restrict__ Bt,
             const float* __restrict__ b0, const float* __restrict__ b1p,
             const float* __restrict__ b2p, void* __restrict__ Cout,
             int M, int N, int ldk, int kchunk)
{
  __shared__ __align__(16) bf16 Smem[2][128 * 64];  // As (16K) + bounce room
  bf16* As = Smem[0];
  const int t = threadIdx.x;
  const int wave = t >> 6, lane = t & 63;
  const int lm = lane & 15, qd = lane >> 4;
  const int wm = (wave >> 1) * 64, wn = (wave & 1) * 64;

  // XCD swizzle: lin2d = q*8 + x  ->  swz = x*cpx + q (bijection, nwg2d%8==0)
  const int nwg2d = gridDim.x * gridDim.y;
  const int cpx = nwg2d >> 3;
  const int lin2d = blockIdx.x + gridDim.x * blockIdx.y;
  const int swz = (lin2d & 7) * cpx + (lin2d >> 3);
  const int bxs = swz % gridDim.x;
  const int bys = swz / gridDim.x;
  const int bm = bys * 128, bn = bxs * 128;
  const int kbeg = blockIdx.z * kchunk;

  f32x4 acc[4][4] = {};
  const int srow = t >> 3;
  const int schk = t & 7;

  // per-lane B fragment base: row = bn + wn + nt*16 + lm, col offset qd*8
  const bf16* bbase = Bt + (size_t)(bn + wn + lm) * ldk + qd * 8;

  for (int k0 = kbeg; k0 < kbeg + kchunk; k0 += 64) {
#pragma unroll
    for (int r = 0; r < 4; ++r) {
      const int row = r * 32 + srow;
      const int chunk = schk ^ (row & 7);
      async_load16(A + (size_t)(bm + row) * ldk + (k0 + chunk * 8),
                   (bf16*)((char*)As + r * 4096 + t * 16));
    }
    // direct B fragment loads (global, L2-hot); complete under the barrier's
    // vmcnt drain alongside A staging.
    bf16x8 bv[2][4];
#pragma unroll
    for (int ks = 0; ks < 2; ++ks)
#pragma unroll
      for (int nt = 0; nt < 4; ++nt)
        bv[ks][nt] = *(const bf16x8*)(bbase + (size_t)(nt * 16) * ldk + k0 + ks * 32);
    __syncthreads();
#pragma unroll
    for (int ks = 0; ks < 2; ++ks) {
      bf16x8 av[4];
#pragma unroll
      for (int mt = 0; mt < 4; ++mt) {
        const int row = wm + mt * 16 + lm;
        const int chunk = (ks * 4 + qd) ^ (row & 7);
        av[mt] = *(const bf16x8*)(As + row * 64 + chunk * 8);
      }
#pragma unroll
      for (int mt = 0; mt < 4; ++mt)
#pragma unroll
        for (int nt = 0; nt < 4; ++nt)
          acc[mt][nt] = __builtin_amdgcn_mfma_f32_16x16x32_bf16(bv[ks][nt], av[mt], acc[mt][nt], 0, 0, 0);
    }
    __syncthreads();
  }

  // ------------------------- epilogue: per-wave LDS bounce, coalesced stores
  // After the loop's final __syncthreads(), all waves are done reading As
  // -> safe to overwrite. Wave w owns Smem elems [w*4096, (w+1)*4096).
  bf16* tw = &Smem[0][0] + wave * 4096;  // 64x64 bf16 tile, row-major ld=64
  const bool vt = (EPI == 3) && ((bn + wn) >= 2 * HDIM);  // V section (uniform per wave)

#pragma unroll
  for (int nt = 0; nt < 4; ++nt) {
    const int n0 = bn + wn + nt * 16 + qd * 4;
    f32x4 bsv = {0.f, 0.f, 0.f, 0.f};
    if (EPI == 2) bsv = *(const f32x4*)(b0 + n0);
    if (EPI == 3) {
      const int sect = n0 >> 10, c = n0 & 1023;
      const float* bp = (sect == 0) ? b0 : (sect == 1) ? b1p : b2p;
      bsv = *(const f32x4*)(bp + c);
    }
#pragma unroll
    for (int mt = 0; mt < 4; ++mt) {
      f32x4 v;
#pragma unroll
      for (int r = 0; r < 4; ++r) v[r] = acc[mt][nt][r] + bsv[r];
      bf16x4 o;
      if (EPI == 2) {
#pragma unroll
        for (int r = 0; r < 4; ++r) {
          const float z = v[r] * 0.70710678118f;
          const float az = fabsf(z);
          const float tt = __builtin_amdgcn_rcpf(fmaf(az, 0.3275911f, 1.0f));
          const float poly = tt * fmaf(tt, fmaf(tt, fmaf(tt, fmaf(tt, 1.061405429f,
                             -1.453152027f), 1.421413741f), -0.284496736f), 0.254829592f);
          const float e = __builtin_amdgcn_exp2f(az * az * -1.4426950408889634f);
          float erfv = 1.0f - poly * e;
          erfv = (z < 0.f) ? -erfv : erfv;
          o[r] = (bf16)(0.5f * v[r] * (1.0f + erfv));
        }
      } else {
#pragma unroll
        for (int r = 0; r < 4; ++r) o[r] = (bf16)v[r];
      }
      if (!vt) {
        // tile[m-row][n-col]
        *(bf16x4*)(tw + (mt * 16 + lm) * 64 + nt * 16 + qd * 4) = o;
      } else {
        // transposed: tile[d(=n)][s(=m)] so global stores run along s
#pragma unroll
        for (int r = 0; r < 4; ++r)
          tw[(nt * 16 + qd * 4 + r) * 64 + mt * 16 + lm] = o[r];
      }
    }
  }
  // No barrier needed: each wave reads only its own tile (lgkmcnt handles
  // the ds_write->ds_read ordering within the wave).
  const int erow = lane >> 3, ech = lane & 7;
  if (EPI == 1) {
    bf16* dst = (bf16*)Cout + (size_t)blockIdx.z * M * N +
                (size_t)(bm + wm) * N + (bn + wn);
#pragma unroll
    for (int p = 0; p < 8; ++p) {
      const int row = p * 8 + erow;
      bf16x8 val = *(const bf16x8*)(tw + row * 64 + ech * 8);
      *(bf16x8*)(dst + (size_t)row * N + ech * 8) = val;
    }
  } else if (EPI == 2) {
    bf16* dst = (bf16*)Cout + (size_t)(bm + wm) * N + (bn + wn);
#pragma unroll
    for (int p = 0; p < 8; ++p) {
      const int row = p * 8 + erow;
      bf16x8 val = *(const bf16x8*)(tw + row * 64 + ech * 8);
      *(bf16x8*)(dst + (size_t)row * N + ech * 8) = val;
    }
  } else {
    bf16* base = (bf16*)Cout;
    const int sect = (bn + wn) >> 10;
    if (!vt) {
      bf16* dst = base + (size_t)sect * M_TOK * HDIM +
                  (size_t)(bm + wm) * HDIM + ((bn + wn) & 1023);
#pragma unroll
      for (int p = 0; p < 8; ++p) {
        const int row = p * 8 + erow;
        bf16x8 val = *(const bf16x8*)(tw + row * 64 + ech * 8);
        *(bf16x8*)(dst + (size_t)row * HDIM + ech * 8) = val;
      }
    } else {
      const int c0 = (bn + wn) & 1023;
      const int hh = c0 >> 6;
      const int bb = (bm + wm) >> 11, ss0 = (bm + wm) & 2047;
      bf16* dst = base + (size_t)2 * M_TOK * HDIM +
                  (size_t)((bb * NHEAD + hh) * HD) * SEQ + ss0;
#pragma unroll
      for (int p = 0; p < 8; ++p) {
        const int row = p * 8 + erow;  // d within head
        bf16x8 val = *(const bf16x8*)(tw + row * 64 + ech * 8);
        *(bf16x8*)(dst + (size_t)row * SEQ + ech * 8) = val;
      }
    }
  }
}

// ---------------------------------------------------------------- flash attention
// Round-0 verified structure (NSPLIT=4, 2048 blocks): LDS-staged K/V,
// register-P, 32 q/wave, XCD swizzle, bf16 partials, l via ones-MFMA.
__global__ __launch_bounds__(256)
void attn_kernel(const bf16* __restrict__ Q, const bf16* __restrict__ Kg,
                 const bf16* __restrict__ Vt, const int* __restrict__ mask,
                 bf16* __restrict__ Po, float* __restrict__ Lp)
{
  __shared__ __align__(16) bf16 Ks[64 * 64];   // [key][d], chunk-swizzled
  __shared__ __align__(16) bf16 Vs[64 * 64];   // [d][key], chunk-swizzled
  __shared__ float madd[64];

  const int t = threadIdx.x;
  const int wave = t >> 6, lane = t & 63;
  const int lm = lane & 15, qd = lane >> 4;

  // XCD-aware decode: group g = (lin&7)*16 + (lin>>7); qblk = (lin>>3)&15.
  const int lin = blockIdx.x;
  const int g = (lin & 7) * 16 + (lin >> 7);
  const int qblk = (lin >> 3) & 15;
  const int bh = g >> 2;
  const int split = g & 3;
  const int b = bh >> 4, h = bh & 15;
  const int q0 = qblk * 128 + wave * 32;
  const int kv_beg = split * (SEQ / NSPLIT);

  bf16x8 qf[2][2];
#pragma unroll
  for (int qt = 0; qt < 2; ++qt)
#pragma unroll
    for (int ks = 0; ks < 2; ++ks)
      qf[qt][ks] = *(const bf16x8*)(Q + (size_t)(b * SEQ + q0 + qt * 16 + lm) * HDIM +
                                    h * HD + ks * 32 + qd * 8);

  const bf16 onev = (bf16)1.0f;
  const bf16x4 ones = {onev, onev, onev, onev};
  f32x4 lacc[2] = {};      // l via MFMA: all entries = colsum for q=lm
  f32x4 oacc[2][4] = {};   // [qt][nt2] O^T: d = nt2*16+qd*4+r, q = lm

  const int srow = t >> 3, schk = t & 7;
  const float C = 0.1803368801f;  // log2(e)/8

  for (int kv0 = kv_beg; kv0 < kv_beg + SEQ / NSPLIT; kv0 += 64) {
#pragma unroll
    for (int r = 0; r < 2; ++r) {
      const int row = r * 32 + srow;
      const int g2 = schk ^ (row & 7);
      async_load16(Kg + (size_t)(b * SEQ + kv0 + row) * HDIM + h * HD + g2 * 8,
                   (bf16*)((char*)Ks + r * 4096 + t * 16));
      async_load16(Vt + (size_t)(bh * HD + row) * SEQ + kv0 + g2 * 8,
                   (bf16*)((char*)Vs + r * 4096 + t * 16));
    }
    if (t < 64) madd[t] = (mask[b * SEQ + kv0 + t] == 1) ? 0.f : -1.0e30f;
    __syncthreads();

    bf16x8 kf[2][4];
#pragma unroll
    for (int ks = 0; ks < 2; ++ks)
#pragma unroll
      for (int nt = 0; nt < 4; ++nt) {
        const int row = nt * 16 + lm;
        const int c = (ks * 4 + qd) ^ (row & 7);
        kf[ks][nt] = *(const bf16x8*)(Ks + row * 64 + c * 8);
      }

    bf16x4 pf[2][4];
#pragma unroll
    for (int qt = 0; qt < 2; ++qt) {
      f32x4 sacc[4] = {};
#pragma unroll
      for (int ks = 0; ks < 2; ++ks)
#pragma unroll
        for (int nt = 0; nt < 4; ++nt)
          sacc[nt] = __builtin_amdgcn_mfma_f32_16x16x32_bf16(kf[ks][nt], qf[qt][ks], sacc[nt], 0, 0, 0);
#pragma unroll
      for (int nt = 0; nt < 4; ++nt) {
        f32x4 ma = *(const f32x4*)(madd + nt * 16 + qd * 4);
#pragma unroll
        for (int r = 0; r < 4; ++r)
          pf[qt][nt][r] = (bf16)__builtin_amdgcn_exp2f(fmaf(sacc[nt][r], C, ma[r]));
        lacc[qt] = mfma16_bf16(ones, pf[qt][nt], lacc[qt]);
      }
    }

#pragma unroll
    for (int nt2 = 0; nt2 < 4; ++nt2) {
      const int row = nt2 * 16 + lm;
#pragma unroll
      for (int nt = 0; nt < 4; ++nt) {
        bf16x4 vf = *(const bf16x4*)(Vs + row * 64 +
                     (((nt * 2 + (qd >> 1)) ^ (row & 7)) * 8) + (qd & 1) * 4);
        oacc[0][nt2] = mfma16_bf16(vf, pf[0][nt], oacc[0][nt2]);
        oacc[1][nt2] = mfma16_bf16(vf, pf[1][nt], oacc[1][nt2]);
      }
    }
    __syncthreads();
  }

  bf16* po = Po + (size_t)(split * 32 + bh) * 64 * SEQ;
#pragma unroll
  for (int qt = 0; qt < 2; ++qt) {
#pragma unroll
    for (int nt2 = 0; nt2 < 4; ++nt2)
#pragma unroll
      for (int r = 0; r < 4; ++r)
        po[(size_t)(nt2 * 16 + qd * 4 + r) * SEQ + q0 + qt * 16 + lm] =
            (bf16)oacc[qt][nt2][r];
    if (qd == 0)
      Lp[(size_t)(split * 32 + bh) * SEQ + q0 + qt * 16 + lm] = lacc[qt][0];
  }
}

// ------------------------------- attn merge via LDS tile: coalesced reads along s
__global__ __launch_bounds__(256)
void attn_merge(const bf16* __restrict__ Po, const float* __restrict__ Lp,
                bf16* __restrict__ Aout)
{
  __shared__ bf16 tile[64][80];  // [s][d], 80-elem rows -> 160B, 16B-aligned
  __shared__ float linv[64];
  const int t = threadIdx.x;
  const int bh = blockIdx.y;
  const int b = bh >> 4, h = bh & 15;
  const int s0 = blockIdx.x * 64;

  if (t < 64) {
    float l = 0.f;
#pragma unroll
    for (int s = 0; s < NSPLIT; ++s)
      l += Lp[(size_t)(s * 32 + bh) * SEQ + s0 + t];
    linv[t] = 1.0f / l;
  }
  __syncthreads();

#pragma unroll
  for (int it = 0; it < 2; ++it) {
    const int d = (t >> 3) + 32 * it;
    const int sc = (t & 7) * 8;
    float acc[8] = {};
#pragma unroll
    for (int s = 0; s < NSPLIT; ++s) {
      bf16x8 v = *(const bf16x8*)(Po + ((size_t)(s * 32 + bh) * 64 + d) * SEQ + s0 + sc);
#pragma unroll
      for (int j = 0; j < 8; ++j) acc[j] += (float)v[j];
    }
#pragma unroll
    for (int j = 0; j < 8; ++j)
      tile[sc + j][d] = (bf16)(acc[j] * linv[sc + j]);
  }
  __syncthreads();

  const int tok = t >> 2, dc = (t & 3) * 16;
  bf16x8 o0 = *(const bf16x8*)&tile[tok][dc];
  bf16x8 o1 = *(const bf16x8*)&tile[tok][dc + 8];
  bf16* dst = Aout + (size_t)(b * SEQ + s0 + tok) * HDIM + h * HD + dc;
  *(bf16x8*)dst = o0;
  *(bf16x8*)(dst + 8) = o1;
}

// ------------------------------- layernorm over H=1024, summing NP bf16 partials + bias
template<int NP, int OUT_BF16>
__global__ __launch_bounds__(256)
void ln_sum(const bf16* __restrict__ p, const float* __restrict__ bias,
            const float* __restrict__ gamma, const float* __restrict__ beta,
            void* __restrict__ out)
{
  const int row = blockIdx.x;
  const int t = threadIdx.x;
  f32x4 v = {0.f, 0.f, 0.f, 0.f};
#pragma unroll
  for (int np = 0; np < NP; ++np) {
    bf16x4 u = *(const bf16x4*)(p + np * PSTRIDE + (size_t)row * HDIM + t * 4);
#pragma unroll
    for (int j = 0; j < 4; ++j) v[j] += (float)u[j];
  }
  f32x4 bv0 = *(const f32x4*)(bias + t * 4);
#pragma unroll
  for (int j = 0; j < 4; ++j) v[j] += bv0[j];

  float s = v[0] + v[1] + v[2] + v[3];
  float s2 = v[0] * v[0] + v[1] * v[1] + v[2] * v[2] + v[3] * v[3];
#pragma unroll
  for (int d = 1; d < 64; d <<= 1) { s += __shfl_xor(s, d, 64); s2 += __shfl_xor(s2, d, 64); }
  __shared__ float ss[4], ss2[4];
  const int wave = t >> 6, lane = t & 63;
  if (lane == 0) { ss[wave] = s; ss2[wave] = s2; }
  __syncthreads();
  s = ss[0] + ss[1] + ss[2] + ss[3];
  s2 = ss2[0] + ss2[1] + ss2[2] + ss2[3];
  const float mean = s * (1.0f / HDIM);
  const float var = s2 * (1.0f / HDIM) - mean * mean;
  const float rstd = rsqrtf(var + 1e-12f);
  f32x4 gv = *(const f32x4*)(gamma + t * 4);
  f32x4 bv = *(const f32x4*)(beta + t * 4);
  f32x4 y;
#pragma unroll
  for (int j = 0; j < 4; ++j) y[j] = gv[j] * (v[j] - mean) * rstd + bv[j];
  if (OUT_BF16) {
    bf16x4 o;
#pragma unroll
    for (int j = 0; j < 4; ++j) o[j] = (bf16)y[j];
    *(bf16x4*)((bf16*)out + (size_t)row * HDIM + t * 4) = o;
  } else {
    *(f32x4*)((float*)out + (size_t)row * HDIM + t * 4) = y;
  }
}

// ---------------------------------------------------------------- launch
extern "C" void kernel_launch(void* const* d_in, const int* in_sizes, int n_in,
                              void* d_out, int out_size, void* d_ws, size_t ws_size,
                              hipStream_t stream)
{
  const float* x    = (const float*)d_in[0];
  const int*   am   = (const int*)d_in[1];
  const float* Wq   = (const float*)d_in[2];
  const float* bq   = (const float*)d_in[3];
  const float* Wk   = (const float*)d_in[4];
  const float* bk   = (const float*)d_in[5];
  const float* Wv   = (const float*)d_in[6];
  const float* bv   = (const float*)d_in[7];
  const float* Wo   = (const float*)d_in[8];
  const float* bo   = (const float*)d_in[9];
  const float* ln1g = (const float*)d_in[10];
  const float* ln1b = (const float*)d_in[11];
  const float* W1   = (const float*)d_in[12];
  const float* b1   = (const float*)d_in[13];
  const float* W2   = (const float*)d_in[14];
  const float* b2   = (const float*)d_in[15];
  const float* ln2g = (const float*)d_in[16];
  const float* ln2b = (const float*)d_in[17];

  char* ws = (char*)d_ws;
  const size_t MB = 1ull << 20;
  bf16*  W1T  = (bf16*)(ws + 0 * MB);    // 8 MiB
  bf16*  W2T  = (bf16*)(ws + 8 * MB);    // 8 MiB
  bf16*  Xb   = (bf16*)(ws + 16 * MB);   // 8 MiB (dead after QKV)
  bf16*  QKVT = (bf16*)(ws + 24 * MB);   // 8 MiB (WoT = last quarter)
  bf16*  WoT  = QKVT + (size_t)3 * HDIM * HDIM;
  bf16*  Qb   = (bf16*)(ws + 33 * MB);   // Q(33-41), K(41-49), Vt(49-57)
  bf16*  Kb   = (bf16*)(ws + 41 * MB);
  bf16*  Vtb  = (bf16*)(ws + 49 * MB);
  bf16*  Po   = (bf16*)(ws + 57 * MB);   // 32 MiB attn O^T bf16 partials (57-89)
  float* Lp   = (float*)(ws + 89 * MB);  // 1 MiB l partials (4 splits)
  bf16*  Ab   = (bf16*)(ws + 16 * MB);   // merge out, reuse Xb
  bf16*  Pw   = (bf16*)(ws + 33 * MB);   // Wo bf16 partials 33-49 (Q/K dead)
  bf16*  L1   = (bf16*)(ws + 65 * MB);   // 8 MiB
  bf16*  F1   = (bf16*)(ws + 16 * MB);   // 32 MiB (16-48)
  bf16*  Pf   = (bf16*)(ws + 48 * MB);   // FFN2 bf16 partials 48-80

  prep_kernel<<<dim3(32, 32, 13), 256, 0, stream>>>(x, Wq, Wk, Wv, Wo, W1, W2,
                                                    Xb, QKVT, W1T, W2T);

  gemm_bt<3><<<dim3(3072 / 128, M_TOK / 128, 1), 256, 0, stream>>>(
      Xb, QKVT, bq, bk, bv, Qb, M_TOK, 3072, HDIM, HDIM);

  attn_kernel<<<dim3(2048, 1, 1), 256, 0, stream>>>(Qb, Kb, Vtb, am, Po, Lp);
  attn_merge<<<dim3(SEQ / 64, BATCH * NHEAD), 256, 0, stream>>>(Po, Lp, Ab);

  gemm_bt<1><<<dim3(HDIM / 128, M_TOK / 128, 2), 256, 0, stream>>>(
      Ab, WoT, nullptr, nullptr, nullptr, Pw, M_TOK, HDIM, HDIM, 512);
  ln_sum<2, 1><<<M_TOK, 256, 0, stream>>>(Pw, bo, ln1g, ln1b, L1);

  gemm_bt<2><<<dim3(FFDIM / 128, M_TOK / 128, 1), 256, 0, stream>>>(
      L1, W1T, b1, nullptr, nullptr, F1, M_TOK, FFDIM, HDIM, HDIM);

  gemm_bt<1><<<dim3(HDIM / 128, M_TOK / 128, 4), 256, 0, stream>>>(
      F1, W2T, nullptr, nullptr, nullptr, Pf, M_TOK, HDIM, FFDIM, 1024);
  ln_sum<4, 0><<<M_TOK, 256, 0, stream>>>(Pf, b2, ln2g, ln2b, (float*)d_out);
}

// Round 7
// 345.175 us; speedup vs baseline: 1.3685x; 1.3685x over previous
//
#include <hip/hip_runtime.h>
#include <hip/hip_bf16.h>
#include <math.h>

typedef __bf16 bf16;
typedef __attribute__((ext_vector_type(8))) __bf16 bf16x8;
typedef __attribute__((ext_vector_type(4))) __bf16 bf16x4;
typedef __attribute__((ext_vector_type(2))) __bf16 bf16x2;
typedef __attribute__((ext_vector_type(4))) float f32x4;
typedef __attribute__((ext_vector_type(4))) short short4v;

#define HDIM 1024
#define NHEAD 16
#define HD 64
#define FFDIM 4096
#define BATCH 2
#define SEQ 2048
#define M_TOK 4096  // BATCH*SEQ
#define NSPLIT 4
#define PSTRIDE ((size_t)M_TOK * HDIM)  // elements between split-K partials

static __device__ __forceinline__ void async_load16(const bf16* g, bf16* l) {
  __builtin_amdgcn_global_load_lds(
      (const __attribute__((address_space(1))) void*)g,
      (__attribute__((address_space(3))) void*)l, 16, 0, 0);
}

// 16x16x16 bf16 MFMA wrapper (attn uses it). Host pass has no amdgcn builtins.
static __device__ __forceinline__ f32x4 mfma16_bf16(bf16x4 a, bf16x4 b, f32x4 c) {
#if defined(__HIP_DEVICE_COMPILE__)
#if __has_builtin(__builtin_amdgcn_mfma_f32_16x16x16bf16_1k)
  return __builtin_amdgcn_mfma_f32_16x16x16bf16_1k(
      __builtin_bit_cast(short4v, a), __builtin_bit_cast(short4v, b), c, 0, 0, 0);
#else
  return __builtin_amdgcn_mfma_f32_16x16x16_bf16(a, b, c, 0, 0, 0);
#endif
#else
  return c;  // host pass: never executed
#endif
}

// ---------------------------------------------------------------- prep: all transposes + x cast
// z 0..3: Wq/Wk/Wv/Wo -> QKVT; z 4..7: W1 -> W1T; z 8..11: W2 -> W2T; z 12: cast x
__global__ __launch_bounds__(256)
void prep_kernel(const float* __restrict__ x,
                 const float* __restrict__ Wq, const float* __restrict__ Wk,
                 const float* __restrict__ Wv, const float* __restrict__ Wo,
                 const float* __restrict__ W1, const float* __restrict__ W2,
                 bf16* __restrict__ Xb, bf16* __restrict__ QKVT,
                 bf16* __restrict__ W1T, bf16* __restrict__ W2T)
{
  const int z = blockIdx.z;
  const int t = threadIdx.x;
  if (z == 12) {
    const size_t base = ((size_t)(blockIdx.y * 32 + blockIdx.x)) * 4096;
#pragma unroll
    for (int j = 0; j < 4; ++j) {
      const size_t i = base + j * 1024 + t * 4;
      f32x4 v = *(const f32x4*)(x + i);
      bf16x4 o;
#pragma unroll
      for (int k = 0; k < 4; ++k) o[k] = (bf16)v[k];
      *(bf16x4*)(Xb + i) = o;
    }
    return;
  }
  const float* ps; bf16* pd; int sld, dld;
  if (z < 4) {
    ps = (z == 0) ? Wq : (z == 1) ? Wk : (z == 2) ? Wv : Wo;
    pd = QKVT + (size_t)z * HDIM * HDIM; sld = 1024; dld = 1024;
  } else if (z < 8) {
    const int c = z - 4;
    ps = W1 + c * 1024; sld = 4096;
    pd = W1T + (size_t)c * 1024 * 1024; dld = 1024;
  } else {
    const int c = z - 8;
    ps = W2 + (size_t)c * 1024 * 1024; sld = 1024;
    pd = W2T + c * 1024; dld = 4096;
  }
  __shared__ float tile[32][33];
  const int tx = t & 31, ty = t >> 5;
  const int c0 = blockIdx.x * 32, r0 = blockIdx.y * 32;
#pragma unroll
  for (int i = 0; i < 32; i += 8)
    tile[ty + i][tx] = ps[(size_t)(r0 + ty + i) * sld + c0 + tx];
  __syncthreads();
  const int rr0 = (t & 15) * 2;
  const int ccb = t >> 4;  // 0..15
#pragma unroll
  for (int i = 0; i < 2; ++i) {
    const int cc = ccb + 16 * i;
    bf16x2 v = {(bf16)tile[rr0][cc], (bf16)tile[rr0 + 1][cc]};
    *(bf16x2*)(pd + (size_t)(c0 + cc) * dld + r0 + rr0) = v;
  }
}

// ---------------------------------------------------------------- GEMM  C = A @ Bt^T (+ bias)
// 128x128 tile, 4 waves (2x2 of 64x64), 64KiB LDS, simple 2-barrier loop
// (the verified ~4-blocks/CU implicit-overlap structure), LDS-bounce
// epilogue, XCD swizzle.
// Round-6 lesson (REVERTED): loading B fragments directly from global
// (skipping LDS) regressed 353->472us — FETCH_SIZE blew up (L2 stopped
// absorbing the per-wave re-reads); Bs-in-LDS is an L2-traffic filter.
// Round-7: XOR-swizzle the bounce tile. The un-swizzled bounce put all 16
// lm-lanes at the same tile column (row stride 128B = bank-neutral) ->
// 16-way ds_write conflict, measured 3.9M conflict-cycles/dispatch (R6).
// Store logical (R,C) at R*64 + (C ^ ((R&7)<<3)); read with the same XOR.
// Reads become conflict-free (each 8-lane group covers all 32 banks);
// writes drop to <=4-way residual. Bijective per row; 4/8-elem aligned
// blocks stay aligned.
// EPI: 1 = bf16 partial (no bias, out + z*M*N), 2 = bias+gelu(A&S erf)->bf16,
//      3 = QKV fused epilogue (V stored transposed -> Vt[d][s])
#define BSW(R, C) ((R) * 64 + ((C) ^ (((R) & 7) << 3)))

template<int EPI>
__global__ __launch_bounds__(256)
void gemm_bt(const bf16* __restrict__ A, const bf16* __restrict__ Bt,
             const float* __restrict__ b0, const float* __restrict__ b1p,
             const float* __restrict__ b2p, void* __restrict__ Cout,
             int M, int N, int ldk, int kchunk)
{
  __shared__ __align__(16) bf16 Smem[2][128 * 64];  // As | Bs, contiguous 32KiB
  bf16* As = Smem[0];
  bf16* Bs = Smem[1];
  const int t = threadIdx.x;
  const int wave = t >> 6, lane = t & 63;
  const int lm = lane & 15, qd = lane >> 4;
  const int wm = (wave >> 1) * 64, wn = (wave & 1) * 64;

  // XCD swizzle: lin2d = q*8 + x  ->  swz = x*cpx + q (bijection, nwg2d%8==0)
  const int nwg2d = gridDim.x * gridDim.y;
  const int cpx = nwg2d >> 3;
  const int lin2d = blockIdx.x + gridDim.x * blockIdx.y;
  const int swz = (lin2d & 7) * cpx + (lin2d >> 3);
  const int bxs = swz % gridDim.x;
  const int bys = swz / gridDim.x;
  const int bm = bys * 128, bn = bxs * 128;
  const int kbeg = blockIdx.z * kchunk;

  f32x4 acc[4][4] = {};
  const int srow = t >> 3;
  const int schk = t & 7;

  for (int k0 = kbeg; k0 < kbeg + kchunk; k0 += 64) {
#pragma unroll
    for (int r = 0; r < 4; ++r) {
      const int row = r * 32 + srow;
      const int chunk = schk ^ (row & 7);
      async_load16(A + (size_t)(bm + row) * ldk + (k0 + chunk * 8),
                   (bf16*)((char*)As + r * 4096 + t * 16));
    }
#pragma unroll
    for (int r = 0; r < 4; ++r) {
      const int row = r * 32 + srow;
      const int chunk = schk ^ (row & 7);
      async_load16(Bt + (size_t)(bn + row) * ldk + (k0 + chunk * 8),
                   (bf16*)((char*)Bs + r * 4096 + t * 16));
    }
    __syncthreads();
#pragma unroll
    for (int ks = 0; ks < 2; ++ks) {
      bf16x8 av[4], bv[4];
#pragma unroll
      for (int mt = 0; mt < 4; ++mt) {
        const int row = wm + mt * 16 + lm;
        const int chunk = (ks * 4 + qd) ^ (row & 7);
        av[mt] = *(const bf16x8*)(As + row * 64 + chunk * 8);
      }
#pragma unroll
      for (int nt = 0; nt < 4; ++nt) {
        const int row = wn + nt * 16 + lm;
        const int chunk = (ks * 4 + qd) ^ (row & 7);
        bv[nt] = *(const bf16x8*)(Bs + row * 64 + chunk * 8);
      }
#pragma unroll
      for (int mt = 0; mt < 4; ++mt)
#pragma unroll
        for (int nt = 0; nt < 4; ++nt)
          acc[mt][nt] = __builtin_amdgcn_mfma_f32_16x16x32_bf16(bv[nt], av[mt], acc[mt][nt], 0, 0, 0);
    }
    __syncthreads();
  }

  // ------------------------- epilogue: per-wave LDS bounce, coalesced stores
  // After the loop's final __syncthreads(), all waves are done reading
  // As/Bs -> safe to overwrite. Wave w owns Smem elems [w*4096, (w+1)*4096).
  bf16* tw = &Smem[0][0] + wave * 4096;  // 64x64 bf16 tile, XOR-swizzled
  const bool vt = (EPI == 3) && ((bn + wn) >= 2 * HDIM);  // V section (uniform per wave)

#pragma unroll
  for (int nt = 0; nt < 4; ++nt) {
    const int n0 = bn + wn + nt * 16 + qd * 4;
    f32x4 bsv = {0.f, 0.f, 0.f, 0.f};
    if (EPI == 2) bsv = *(const f32x4*)(b0 + n0);
    if (EPI == 3) {
      const int sect = n0 >> 10, c = n0 & 1023;
      const float* bp = (sect == 0) ? b0 : (sect == 1) ? b1p : b2p;
      bsv = *(const f32x4*)(bp + c);
    }
#pragma unroll
    for (int mt = 0; mt < 4; ++mt) {
      f32x4 v;
#pragma unroll
      for (int r = 0; r < 4; ++r) v[r] = acc[mt][nt][r] + bsv[r];
      bf16x4 o;
      if (EPI == 2) {
#pragma unroll
        for (int r = 0; r < 4; ++r) {
          const float z = v[r] * 0.70710678118f;
          const float az = fabsf(z);
          const float tt = __builtin_amdgcn_rcpf(fmaf(az, 0.3275911f, 1.0f));
          const float poly = tt * fmaf(tt, fmaf(tt, fmaf(tt, fmaf(tt, 1.061405429f,
                             -1.453152027f), 1.421413741f), -0.284496736f), 0.254829592f);
          const float e = __builtin_amdgcn_exp2f(az * az * -1.4426950408889634f);
          float erfv = 1.0f - poly * e;
          erfv = (z < 0.f) ? -erfv : erfv;
          o[r] = (bf16)(0.5f * v[r] * (1.0f + erfv));
        }
      } else {
#pragma unroll
        for (int r = 0; r < 4; ++r) o[r] = (bf16)v[r];
      }
      if (!vt) {
        // tile[m-row][n-col], swizzled (4-elem block stays aligned: XOR is
        // 8-elem-aligned and doesn't touch bits 0-2)
        *(bf16x4*)(tw + BSW(mt * 16 + lm, nt * 16 + qd * 4)) = o;
      } else {
        // transposed: tile[d(=n)][s(=m)] so global stores run along s
#pragma unroll
        for (int r = 0; r < 4; ++r)
          tw[BSW(nt * 16 + qd * 4 + r, mt * 16 + lm)] = o[r];
      }
    }
  }
  // No barrier needed: each wave reads only its own tile (lgkmcnt handles
  // the ds_write->ds_read ordering within the wave).
  const int erow = lane >> 3, ech = lane & 7;
  if (EPI == 1) {
    bf16* dst = (bf16*)Cout + (size_t)blockIdx.z * M * N +
                (size_t)(bm + wm) * N + (bn + wn);
#pragma unroll
    for (int p = 0; p < 8; ++p) {
      const int row = p * 8 + erow;
      bf16x8 val = *(const bf16x8*)(tw + BSW(row, ech * 8));
      *(bf16x8*)(dst + (size_t)row * N + ech * 8) = val;
    }
  } else if (EPI == 2) {
    bf16* dst = (bf16*)Cout + (size_t)(bm + wm) * N + (bn + wn);
#pragma unroll
    for (int p = 0; p < 8; ++p) {
      const int row = p * 8 + erow;
      bf16x8 val = *(const bf16x8*)(tw + BSW(row, ech * 8));
      *(bf16x8*)(dst + (size_t)row * N + ech * 8) = val;
    }
  } else {
    bf16* base = (bf16*)Cout;
    const int sect = (bn + wn) >> 10;
    if (!vt) {
      bf16* dst = base + (size_t)sect * M_TOK * HDIM +
                  (size_t)(bm + wm) * HDIM + ((bn + wn) & 1023);
#pragma unroll
      for (int p = 0; p < 8; ++p) {
        const int row = p * 8 + erow;
        bf16x8 val = *(const bf16x8*)(tw + BSW(row, ech * 8));
        *(bf16x8*)(dst + (size_t)row * HDIM + ech * 8) = val;
      }
    } else {
      const int c0 = (bn + wn) & 1023;
      const int hh = c0 >> 6;
      const int bb = (bm + wm) >> 11, ss0 = (bm + wm) & 2047;
      bf16* dst = base + (size_t)2 * M_TOK * HDIM +
                  (size_t)((bb * NHEAD + hh) * HD) * SEQ + ss0;
#pragma unroll
      for (int p = 0; p < 8; ++p) {
        const int row = p * 8 + erow;  // d within head
        bf16x8 val = *(const bf16x8*)(tw + BSW(row, ech * 8));
        *(bf16x8*)(dst + (size_t)row * SEQ + ech * 8) = val;
      }
    }
  }
}

// ---------------------------------------------------------------- flash attention
// Round-0 verified structure (NSPLIT=4, 2048 blocks): LDS-staged K/V,
// register-P, 32 q/wave, XCD swizzle, bf16 partials, l via ones-MFMA.
__global__ __launch_bounds__(256)
void attn_kernel(const bf16* __restrict__ Q, const bf16* __restrict__ Kg,
                 const bf16* __restrict__ Vt, const int* __restrict__ mask,
                 bf16* __restrict__ Po, float* __restrict__ Lp)
{
  __shared__ __align__(16) bf16 Ks[64 * 64];   // [key][d], chunk-swizzled
  __shared__ __align__(16) bf16 Vs[64 * 64];   // [d][key], chunk-swizzled
  __shared__ float madd[64];

  const int t = threadIdx.x;
  const int wave = t >> 6, lane = t & 63;
  const int lm = lane & 15, qd = lane >> 4;

  // XCD-aware decode: group g = (lin&7)*16 + (lin>>7); qblk = (lin>>3)&15.
  const int lin = blockIdx.x;
  const int g = (lin & 7) * 16 + (lin >> 7);
  const int qblk = (lin >> 3) & 15;
  const int bh = g >> 2;
  const int split = g & 3;
  const int b = bh >> 4, h = bh & 15;
  const int q0 = qblk * 128 + wave * 32;
  const int kv_beg = split * (SEQ / NSPLIT);

  bf16x8 qf[2][2];
#pragma unroll
  for (int qt = 0; qt < 2; ++qt)
#pragma unroll
    for (int ks = 0; ks < 2; ++ks)
      qf[qt][ks] = *(const bf16x8*)(Q + (size_t)(b * SEQ + q0 + qt * 16 + lm) * HDIM +
                                    h * HD + ks * 32 + qd * 8);

  const bf16 onev = (bf16)1.0f;
  const bf16x4 ones = {onev, onev, onev, onev};
  f32x4 lacc[2] = {};      // l via MFMA: all entries = colsum for q=lm
  f32x4 oacc[2][4] = {};   // [qt][nt2] O^T: d = nt2*16+qd*4+r, q = lm

  const int srow = t >> 3, schk = t & 7;
  const float C = 0.1803368801f;  // log2(e)/8

  for (int kv0 = kv_beg; kv0 < kv_beg + SEQ / NSPLIT; kv0 += 64) {
#pragma unroll
    for (int r = 0; r < 2; ++r) {
      const int row = r * 32 + srow;
      const int g2 = schk ^ (row & 7);
      async_load16(Kg + (size_t)(b * SEQ + kv0 + row) * HDIM + h * HD + g2 * 8,
                   (bf16*)((char*)Ks + r * 4096 + t * 16));
      async_load16(Vt + (size_t)(bh * HD + row) * SEQ + kv0 + g2 * 8,
                   (bf16*)((char*)Vs + r * 4096 + t * 16));
    }
    if (t < 64) madd[t] = (mask[b * SEQ + kv0 + t] == 1) ? 0.f : -1.0e30f;
    __syncthreads();

    bf16x8 kf[2][4];
#pragma unroll
    for (int ks = 0; ks < 2; ++ks)
#pragma unroll
      for (int nt = 0; nt < 4; ++nt) {
        const int row = nt * 16 + lm;
        const int c = (ks * 4 + qd) ^ (row & 7);
        kf[ks][nt] = *(const bf16x8*)(Ks + row * 64 + c * 8);
      }

    bf16x4 pf[2][4];
#pragma unroll
    for (int qt = 0; qt < 2; ++qt) {
      f32x4 sacc[4] = {};
#pragma unroll
      for (int ks = 0; ks < 2; ++ks)
#pragma unroll
        for (int nt = 0; nt < 4; ++nt)
          sacc[nt] = __builtin_amdgcn_mfma_f32_16x16x32_bf16(kf[ks][nt], qf[qt][ks], sacc[nt], 0, 0, 0);
#pragma unroll
      for (int nt = 0; nt < 4; ++nt) {
        f32x4 ma = *(const f32x4*)(madd + nt * 16 + qd * 4);
#pragma unroll
        for (int r = 0; r < 4; ++r)
          pf[qt][nt][r] = (bf16)__builtin_amdgcn_exp2f(fmaf(sacc[nt][r], C, ma[r]));
        lacc[qt] = mfma16_bf16(ones, pf[qt][nt], lacc[qt]);
      }
    }

#pragma unroll
    for (int nt2 = 0; nt2 < 4; ++nt2) {
      const int row = nt2 * 16 + lm;
#pragma unroll
      for (int nt = 0; nt < 4; ++nt) {
        bf16x4 vf = *(const bf16x4*)(Vs + row * 64 +
                     (((nt * 2 + (qd >> 1)) ^ (row & 7)) * 8) + (qd & 1) * 4);
        oacc[0][nt2] = mfma16_bf16(vf, pf[0][nt], oacc[0][nt2]);
        oacc[1][nt2] = mfma16_bf16(vf, pf[1][nt], oacc[1][nt2]);
      }
    }
    __syncthreads();
  }

  bf16* po = Po + (size_t)(split * 32 + bh) * 64 * SEQ;
#pragma unroll
  for (int qt = 0; qt < 2; ++qt) {
#pragma unroll
    for (int nt2 = 0; nt2 < 4; ++nt2)
#pragma unroll
      for (int r = 0; r < 4; ++r)
        po[(size_t)(nt2 * 16 + qd * 4 + r) * SEQ + q0 + qt * 16 + lm] =
            (bf16)oacc[qt][nt2][r];
    if (qd == 0)
      Lp[(size_t)(split * 32 + bh) * SEQ + q0 + qt * 16 + lm] = lacc[qt][0];
  }
}

// ------------------------------- attn merge via LDS tile: coalesced reads along s
__global__ __launch_bounds__(256)
void attn_merge(const bf16* __restrict__ Po, const float* __restrict__ Lp,
                bf16* __restrict__ Aout)
{
  __shared__ bf16 tile[64][80];  // [s][d], 80-elem rows -> 160B, 16B-aligned
  __shared__ float linv[64];
  const int t = threadIdx.x;
  const int bh = blockIdx.y;
  const int b = bh >> 4, h = bh & 15;
  const int s0 = blockIdx.x * 64;

  if (t < 64) {
    float l = 0.f;
#pragma unroll
    for (int s = 0; s < NSPLIT; ++s)
      l += Lp[(size_t)(s * 32 + bh) * SEQ + s0 + t];
    linv[t] = 1.0f / l;
  }
  __syncthreads();

#pragma unroll
  for (int it = 0; it < 2; ++it) {
    const int d = (t >> 3) + 32 * it;
    const int sc = (t & 7) * 8;
    float acc[8] = {};
#pragma unroll
    for (int s = 0; s < NSPLIT; ++s) {
      bf16x8 v = *(const bf16x8*)(Po + ((size_t)(s * 32 + bh) * 64 + d) * SEQ + s0 + sc);
#pragma unroll
      for (int j = 0; j < 8; ++j) acc[j] += (float)v[j];
    }
#pragma unroll
    for (int j = 0; j < 8; ++j)
      tile[sc + j][d] = (bf16)(acc[j] * linv[sc + j]);
  }
  __syncthreads();

  const int tok = t >> 2, dc = (t & 3) * 16;
  bf16x8 o0 = *(const bf16x8*)&tile[tok][dc];
  bf16x8 o1 = *(const bf16x8*)&tile[tok][dc + 8];
  bf16* dst = Aout + (size_t)(b * SEQ + s0 + tok) * HDIM + h * HD + dc;
  *(bf16x8*)dst = o0;
  *(bf16x8*)(dst + 8) = o1;
}

// ------------------------------- layernorm over H=1024, summing NP bf16 partials + bias
template<int NP, int OUT_BF16>
__global__ __launch_bounds__(256)
void ln_sum(const bf16* __restrict__ p, const float* __restrict__ bias,
            const float* __restrict__ gamma, const float* __restrict__ beta,
            void* __restrict__ out)
{
  const int row = blockIdx.x;
  const int t = threadIdx.x;
  f32x4 v = {0.f, 0.f, 0.f, 0.f};
#pragma unroll
  for (int np = 0; np < NP; ++np) {
    bf16x4 u = *(const bf16x4*)(p + np * PSTRIDE + (size_t)row * HDIM + t * 4);
#pragma unroll
    for (int j = 0; j < 4; ++j) v[j] += (float)u[j];
  }
  f32x4 bv0 = *(const f32x4*)(bias + t * 4);
#pragma unroll
  for (int j = 0; j < 4; ++j) v[j] += bv0[j];

  float s = v[0] + v[1] + v[2] + v[3];
  float s2 = v[0] * v[0] + v[1] * v[1] + v[2] * v[2] + v[3] * v[3];
#pragma unroll
  for (int d = 1; d < 64; d <<= 1) { s += __shfl_xor(s, d, 64); s2 += __shfl_xor(s2, d, 64); }
  __shared__ float ss[4], ss2[4];
  const int wave = t >> 6, lane = t & 63;
  if (lane == 0) { ss[wave] = s; ss2[wave] = s2; }
  __syncthreads();
  s = ss[0] + ss[1] + ss[2] + ss[3];
  s2 = ss2[0] + ss2[1] + ss2[2] + ss2[3];
  const float mean = s * (1.0f / HDIM);
  const float var = s2 * (1.0f / HDIM) - mean * mean;
  const float rstd = rsqrtf(var + 1e-12f);
  f32x4 gv = *(const f32x4*)(gamma + t * 4);
  f32x4 bv = *(const f32x4*)(beta + t * 4);
  f32x4 y;
#pragma unroll
  for (int j = 0; j < 4; ++j) y[j] = gv[j] * (v[j] - mean) * rstd + bv[j];
  if (OUT_BF16) {
    bf16x4 o;
#pragma unroll
    for (int j = 0; j < 4; ++j) o[j] = (bf16)y[j];
    *(bf16x4*)((bf16*)out + (size_t)row * HDIM + t * 4) = o;
  } else {
    *(f32x4*)((float*)out + (size_t)row * HDIM + t * 4) = y;
  }
}

// ---------------------------------------------------------------- launch
extern "C" void kernel_launch(void* const* d_in, const int* in_sizes, int n_in,
                              void* d_out, int out_size, void* d_ws, size_t ws_size,
                              hipStream_t stream)
{
  const float* x    = (const float*)d_in[0];
  const int*   am   = (const int*)d_in[1];
  const float* Wq   = (const float*)d_in[2];
  const float* bq   = (const float*)d_in[3];
  const float* Wk   = (const float*)d_in[4];
  const float* bk   = (const float*)d_in[5];
  const float* Wv   = (const float*)d_in[6];
  const float* bv   = (const float*)d_in[7];
  const float* Wo   = (const float*)d_in[8];
  const float* bo   = (const float*)d_in[9];
  const float* ln1g = (const float*)d_in[10];
  const float* ln1b = (const float*)d_in[11];
  const float* W1   = (const float*)d_in[12];
  const float* b1   = (const float*)d_in[13];
  const float* W2   = (const float*)d_in[14];
  const float* b2   = (const float*)d_in[15];
  const float* ln2g = (const float*)d_in[16];
  const float* ln2b = (const float*)d_in[17];

  char* ws = (char*)d_ws;
  const size_t MB = 1ull << 20;
  bf16*  W1T  = (bf16*)(ws + 0 * MB);    // 8 MiB
  bf16*  W2T  = (bf16*)(ws + 8 * MB);    // 8 MiB
  bf16*  Xb   = (bf16*)(ws + 16 * MB);   // 8 MiB (dead after QKV)
  bf16*  QKVT = (bf16*)(ws + 24 * MB);   // 8 MiB (WoT = last quarter)
  bf16*  WoT  = QKVT + (size_t)3 * HDIM * HDIM;
  bf16*  Qb   = (bf16*)(ws + 33 * MB);   // Q(33-41), K(41-49), Vt(49-57)
  bf16*  Kb   = (bf16*)(ws + 41 * MB);
  bf16*  Vtb  = (bf16*)(ws + 49 * MB);
  bf16*  Po   = (bf16*)(ws + 57 * MB);   // 32 MiB attn O^T bf16 partials (57-89)
  float* Lp   = (float*)(ws + 89 * MB);  // 1 MiB l partials (4 splits)
  bf16*  Ab   = (bf16*)(ws + 16 * MB);   // merge out, reuse Xb
  bf16*  Pw   = (bf16*)(ws + 33 * MB);   // Wo bf16 partials 33-49 (Q/K dead)
  bf16*  L1   = (bf16*)(ws + 65 * MB);   // 8 MiB
  bf16*  F1   = (bf16*)(ws + 16 * MB);   // 32 MiB (16-48)
  bf16*  Pf   = (bf16*)(ws + 48 * MB);   // FFN2 bf16 partials 48-80

  prep_kernel<<<dim3(32, 32, 13), 256, 0, stream>>>(x, Wq, Wk, Wv, Wo, W1, W2,
                                                    Xb, QKVT, W1T, W2T);

  gemm_bt<3><<<dim3(3072 / 128, M_TOK / 128, 1), 256, 0, stream>>>(
      Xb, QKVT, bq, bk, bv, Qb, M_TOK, 3072, HDIM, HDIM);

  attn_kernel<<<dim3(2048, 1, 1), 256, 0, stream>>>(Qb, Kb, Vtb, am, Po, Lp);
  attn_merge<<<dim3(SEQ / 64, BATCH * NHEAD), 256, 0, stream>>>(Po, Lp, Ab);

  gemm_bt<1><<<dim3(HDIM / 128, M_TOK / 128, 2), 256, 0, stream>>>(
      Ab, WoT, nullptr, nullptr, nullptr, Pw, M_TOK, HDIM, HDIM, 512);
  ln_sum<2, 1><<<M_TOK, 256, 0, stream>>>(Pw, bo, ln1g, ln1b, L1);

  gemm_bt<2><<<dim3(FFDIM / 128, M_TOK / 128, 1), 256, 0, stream>>>(
      L1, W1T, b1, nullptr, nullptr, F1, M_TOK, FFDIM, HDIM, HDIM);

  gemm_bt<1><<<dim3(HDIM / 128, M_TOK / 128, 4), 256, 0, stream>>>(
      F1, W2T, nullptr, nullptr, nullptr, Pf, M_TOK, HDIM, FFDIM, 1024);
  ln_sum<4, 0><<<M_TOK, 256, 0, stream>>>(Pf, b2, ln2g, ln2b, (float*)d_out);
}

// Round 8
// 336.661 us; speedup vs baseline: 1.4031x; 1.0253x over previous
//
#include <hip/hip_runtime.h>
#include <hip/hip_bf16.h>
#include <math.h>

typedef __bf16 bf16;
typedef __attribute__((ext_vector_type(8))) __bf16 bf16x8;
typedef __attribute__((ext_vector_type(4))) __bf16 bf16x4;
typedef __attribute__((ext_vector_type(2))) __bf16 bf16x2;
typedef __attribute__((ext_vector_type(4))) float f32x4;
typedef __attribute__((ext_vector_type(4))) short short4v;

#define HDIM 1024
#define NHEAD 16
#define HD 64
#define FFDIM 4096
#define BATCH 2
#define SEQ 2048
#define M_TOK 4096  // BATCH*SEQ
#define NSPLIT 4
#define PSTRIDE ((size_t)M_TOK * HDIM)  // elements between split-K partials

static __device__ __forceinline__ void async_load16(const bf16* g, bf16* l) {
  __builtin_amdgcn_global_load_lds(
      (const __attribute__((address_space(1))) void*)g,
      (__attribute__((address_space(3))) void*)l, 16, 0, 0);
}

// 16x16x16 bf16 MFMA wrapper (attn uses it). Host pass has no amdgcn builtins.
static __device__ __forceinline__ f32x4 mfma16_bf16(bf16x4 a, bf16x4 b, f32x4 c) {
#if defined(__HIP_DEVICE_COMPILE__)
#if __has_builtin(__builtin_amdgcn_mfma_f32_16x16x16bf16_1k)
  return __builtin_amdgcn_mfma_f32_16x16x16bf16_1k(
      __builtin_bit_cast(short4v, a), __builtin_bit_cast(short4v, b), c, 0, 0, 0);
#else
  return __builtin_amdgcn_mfma_f32_16x16x16_bf16(a, b, c, 0, 0, 0);
#endif
#else
  return c;  // host pass: never executed
#endif
}

static __device__ __forceinline__ float gelu_erf_f(float x) {
  const float z = x * 0.70710678118f;
  const float az = fabsf(z);
  const float tt = __builtin_amdgcn_rcpf(fmaf(az, 0.3275911f, 1.0f));
  const float poly = tt * fmaf(tt, fmaf(tt, fmaf(tt, fmaf(tt, 1.061405429f,
                     -1.453152027f), 1.421413741f), -0.284496736f), 0.254829592f);
  const float e = __builtin_amdgcn_exp2f(az * az * -1.4426950408889634f);
  float erfv = 1.0f - poly * e;
  erfv = (z < 0.f) ? -erfv : erfv;
  return 0.5f * x * (1.0f + erfv);
}

// ---------------------------------------------------------------- prep: all transposes + x cast
__global__ __launch_bounds__(256)
void prep_kernel(const float* __restrict__ x,
                 const float* __restrict__ Wq, const float* __restrict__ Wk,
                 const float* __restrict__ Wv, const float* __restrict__ Wo,
                 const float* __restrict__ W1, const float* __restrict__ W2,
                 bf16* __restrict__ Xb, bf16* __restrict__ QKVT,
                 bf16* __restrict__ W1T, bf16* __restrict__ W2T)
{
  const int z = blockIdx.z;
  const int t = threadIdx.x;
  if (z == 12) {
    const size_t base = ((size_t)(blockIdx.y * 32 + blockIdx.x)) * 4096;
#pragma unroll
    for (int j = 0; j < 4; ++j) {
      const size_t i = base + j * 1024 + t * 4;
      f32x4 v = *(const f32x4*)(x + i);
      bf16x4 o;
#pragma unroll
      for (int k = 0; k < 4; ++k) o[k] = (bf16)v[k];
      *(bf16x4*)(Xb + i) = o;
    }
    return;
  }
  const float* ps; bf16* pd; int sld, dld;
  if (z < 4) {
    ps = (z == 0) ? Wq : (z == 1) ? Wk : (z == 2) ? Wv : Wo;
    pd = QKVT + (size_t)z * HDIM * HDIM; sld = 1024; dld = 1024;
  } else if (z < 8) {
    const int c = z - 4;
    ps = W1 + c * 1024; sld = 4096;
    pd = W1T + (size_t)c * 1024 * 1024; dld = 1024;
  } else {
    const int c = z - 8;
    ps = W2 + (size_t)c * 1024 * 1024; sld = 1024;
    pd = W2T + c * 1024; dld = 4096;
  }
  __shared__ float tile[32][33];
  const int tx = t & 31, ty = t >> 5;
  const int c0 = blockIdx.x * 32, r0 = blockIdx.y * 32;
#pragma unroll
  for (int i = 0; i < 32; i += 8)
    tile[ty + i][tx] = ps[(size_t)(r0 + ty + i) * sld + c0 + tx];
  __syncthreads();
  const int rr0 = (t & 15) * 2;
  const int ccb = t >> 4;  // 0..15
#pragma unroll
  for (int i = 0; i < 2; ++i) {
    const int cc = ccb + 16 * i;
    bf16x2 v = {(bf16)tile[rr0][cc], (bf16)tile[rr0 + 1][cc]};
    *(bf16x2*)(pd + (size_t)(c0 + cc) * dld + r0 + rr0) = v;
  }
}

// ---------------------------------------------------------------- GEMM 128^2 (QKV, Wo)
// Verified 2-barrier structure + swizzled LDS-bounce epilogue + XCD swizzle.
#define BSW(R, C) ((R) * 64 + ((C) ^ (((R) & 7) << 3)))

template<int EPI>
__global__ __launch_bounds__(256)
void gemm_bt(const bf16* __restrict__ A, const bf16* __restrict__ Bt,
             const float* __restrict__ b0, const float* __restrict__ b1p,
             const float* __restrict__ b2p, void* __restrict__ Cout,
             int M, int N, int ldk, int kchunk)
{
  __shared__ __align__(16) bf16 Smem[2][128 * 64];  // As | Bs, contiguous 32KiB
  bf16* As = Smem[0];
  bf16* Bs = Smem[1];
  const int t = threadIdx.x;
  const int wave = t >> 6, lane = t & 63;
  const int lm = lane & 15, qd = lane >> 4;
  const int wm = (wave >> 1) * 64, wn = (wave & 1) * 64;

  const int nwg2d = gridDim.x * gridDim.y;
  const int cpx = nwg2d >> 3;
  const int lin2d = blockIdx.x + gridDim.x * blockIdx.y;
  const int swz = (lin2d & 7) * cpx + (lin2d >> 3);
  const int bxs = swz % gridDim.x;
  const int bys = swz / gridDim.x;
  const int bm = bys * 128, bn = bxs * 128;
  const int kbeg = blockIdx.z * kchunk;

  f32x4 acc[4][4] = {};
  const int srow = t >> 3;
  const int schk = t & 7;

  for (int k0 = kbeg; k0 < kbeg + kchunk; k0 += 64) {
#pragma unroll
    for (int r = 0; r < 4; ++r) {
      const int row = r * 32 + srow;
      const int chunk = schk ^ (row & 7);
      async_load16(A + (size_t)(bm + row) * ldk + (k0 + chunk * 8),
                   (bf16*)((char*)As + r * 4096 + t * 16));
    }
#pragma unroll
    for (int r = 0; r < 4; ++r) {
      const int row = r * 32 + srow;
      const int chunk = schk ^ (row & 7);
      async_load16(Bt + (size_t)(bn + row) * ldk + (k0 + chunk * 8),
                   (bf16*)((char*)Bs + r * 4096 + t * 16));
    }
    __syncthreads();
#pragma unroll
    for (int ks = 0; ks < 2; ++ks) {
      bf16x8 av[4], bv[4];
#pragma unroll
      for (int mt = 0; mt < 4; ++mt) {
        const int row = wm + mt * 16 + lm;
        const int chunk = (ks * 4 + qd) ^ (row & 7);
        av[mt] = *(const bf16x8*)(As + row * 64 + chunk * 8);
      }
#pragma unroll
      for (int nt = 0; nt < 4; ++nt) {
        const int row = wn + nt * 16 + lm;
        const int chunk = (ks * 4 + qd) ^ (row & 7);
        bv[nt] = *(const bf16x8*)(Bs + row * 64 + chunk * 8);
      }
#pragma unroll
      for (int mt = 0; mt < 4; ++mt)
#pragma unroll
        for (int nt = 0; nt < 4; ++nt)
          acc[mt][nt] = __builtin_amdgcn_mfma_f32_16x16x32_bf16(bv[nt], av[mt], acc[mt][nt], 0, 0, 0);
    }
    __syncthreads();
  }

  bf16* tw = &Smem[0][0] + wave * 4096;  // 64x64 bf16 tile, XOR-swizzled
  const bool vt = (EPI == 3) && ((bn + wn) >= 2 * HDIM);

#pragma unroll
  for (int nt = 0; nt < 4; ++nt) {
    const int n0 = bn + wn + nt * 16 + qd * 4;
    f32x4 bsv = {0.f, 0.f, 0.f, 0.f};
    if (EPI == 2) bsv = *(const f32x4*)(b0 + n0);
    if (EPI == 3) {
      const int sect = n0 >> 10, c = n0 & 1023;
      const float* bp = (sect == 0) ? b0 : (sect == 1) ? b1p : b2p;
      bsv = *(const f32x4*)(bp + c);
    }
#pragma unroll
    for (int mt = 0; mt < 4; ++mt) {
      f32x4 v;
#pragma unroll
      for (int r = 0; r < 4; ++r) v[r] = acc[mt][nt][r] + bsv[r];
      bf16x4 o;
      if (EPI == 2) {
#pragma unroll
        for (int r = 0; r < 4; ++r) o[r] = (bf16)gelu_erf_f(v[r]);
      } else {
#pragma unroll
        for (int r = 0; r < 4; ++r) o[r] = (bf16)v[r];
      }
      if (!vt) {
        *(bf16x4*)(tw + BSW(mt * 16 + lm, nt * 16 + qd * 4)) = o;
      } else {
#pragma unroll
        for (int r = 0; r < 4; ++r)
          tw[BSW(nt * 16 + qd * 4 + r, mt * 16 + lm)] = o[r];
      }
    }
  }
  const int erow = lane >> 3, ech = lane & 7;
  if (EPI == 1) {
    bf16* dst = (bf16*)Cout + (size_t)blockIdx.z * M * N +
                (size_t)(bm + wm) * N + (bn + wn);
#pragma unroll
    for (int p = 0; p < 8; ++p) {
      const int row = p * 8 + erow;
      bf16x8 val = *(const bf16x8*)(tw + BSW(row, ech * 8));
      *(bf16x8*)(dst + (size_t)row * N + ech * 8) = val;
    }
  } else if (EPI == 2) {
    bf16* dst = (bf16*)Cout + (size_t)(bm + wm) * N + (bn + wn);
#pragma unroll
    for (int p = 0; p < 8; ++p) {
      const int row = p * 8 + erow;
      bf16x8 val = *(const bf16x8*)(tw + BSW(row, ech * 8));
      *(bf16x8*)(dst + (size_t)row * N + ech * 8) = val;
    }
  } else {
    bf16* base = (bf16*)Cout;
    const int sect = (bn + wn) >> 10;
    if (!vt) {
      bf16* dst = base + (size_t)sect * M_TOK * HDIM +
                  (size_t)(bm + wm) * HDIM + ((bn + wn) & 1023);
#pragma unroll
      for (int p = 0; p < 8; ++p) {
        const int row = p * 8 + erow;
        bf16x8 val = *(const bf16x8*)(tw + BSW(row, ech * 8));
        *(bf16x8*)(dst + (size_t)row * HDIM + ech * 8) = val;
      }
    } else {
      const int c0 = (bn + wn) & 1023;
      const int hh = c0 >> 6;
      const int bb = (bm + wm) >> 11, ss0 = (bm + wm) & 2047;
      bf16* dst = base + (size_t)2 * M_TOK * HDIM +
                  (size_t)((bb * NHEAD + hh) * HD) * SEQ + ss0;
#pragma unroll
      for (int p = 0; p < 8; ++p) {
        const int row = p * 8 + erow;  // d within head
        bf16x8 val = *(const bf16x8*)(tw + BSW(row, ech * 8));
        *(bf16x8*)(dst + (size_t)row * SEQ + ech * 8) = val;
      }
    }
  }
}

// ---------------------------------------------------------------- GEMM 256^2 8-phase (FFN1, FFN2)
// R3's twice-verified vmcnt/barrier structure, with corrected fencing:
// R3's BARX() put sched_barrier(0) on BOTH sides of every s_barrier (16
// full scheduler fences / 2-K-tile iteration) — the m141 order-pinning
// failure mode; measured MfmaUtil 15%. m201's discipline (62% util, same
// barrier count): fence only (a) after the lgkmcnt(0) asm (rule #18 — stop
// MFMA hoisting over unfinished ds_reads) and (b) after each s_barrier
// (stop memory ops hoisting above the barrier). Nothing before barriers.
// Also NEW: LDS-bounce epilogue (Smem dead after final barrier; 8 waves x
// 16KB = exactly the 128KB) — R3's direct stores had the 2.5x write
// inflation fixed in gemm_bt at round 4.
// Only EPI 1 (bf16 partial) and 2 (bias+gelu) instantiated here.

#define STAGE_Q(OP, BASEMN, LDSB, KOFF, Q) do { \
    const int rr_ = (Q) * 64 + (t >> 3); \
    const int gc_ = (t & 7) ^ (rr_ & 7); \
    async_load16((OP) + (size_t)((BASEMN) + rr_) * ldk + (KOFF) + gc_ * 8, \
                 (LDSB) + (Q) * 4096 + t * 8); \
  } while (0)

#define STAGE_HALF(OP, BASEMN, LDSB, KOFF, H) do { \
    STAGE_Q(OP, BASEMN, LDSB, KOFF, 2 * (H)); \
    STAGE_Q(OP, BASEMN, LDSB, KOFF, 2 * (H) + 1); \
  } while (0)

#define LOAD_AV(BUF, MH) do { \
    _Pragma("unroll") \
    for (int mt_ = 0; mt_ < 4; ++mt_) { \
      const int row_ = wm + (MH) * 64 + mt_ * 16 + lm; \
      _Pragma("unroll") \
      for (int ks_ = 0; ks_ < 2; ++ks_) { \
        const int c_ = (ks_ * 4 + qd) ^ (row_ & 7); \
        av[mt_][ks_] = *(const bf16x8*)(As_[BUF] + row_ * 64 + c_ * 8); \
      } \
    } \
  } while (0)

#define LOAD_BV(DST, BUF, NH) do { \
    _Pragma("unroll") \
    for (int nt_ = 0; nt_ < 2; ++nt_) { \
      const int row_ = wnb + (NH) * 32 + nt_ * 16 + lm; \
      _Pragma("unroll") \
      for (int ks_ = 0; ks_ < 2; ++ks_) { \
        const int c_ = (ks_ * 4 + qd) ^ (row_ & 7); \
        DST[nt_][ks_] = *(const bf16x8*)(Bs_[BUF] + row_ * 64 + c_ * 8); \
      } \
    } \
  } while (0)

#define MFMA_Q(MH, BV, NH) do { \
    __builtin_amdgcn_s_setprio(1); \
    _Pragma("unroll") \
    for (int mt_ = 0; mt_ < 4; ++mt_) \
      _Pragma("unroll") \
      for (int nt_ = 0; nt_ < 2; ++nt_) \
        _Pragma("unroll") \
        for (int ks_ = 0; ks_ < 2; ++ks_) \
          acc[(MH) * 4 + mt_][(NH) * 2 + nt_] = \
              __builtin_amdgcn_mfma_f32_16x16x32_bf16( \
                  BV[nt_][ks_], av[mt_][ks_], \
                  acc[(MH) * 4 + mt_][(NH) * 2 + nt_], 0, 0, 0); \
    __builtin_amdgcn_s_setprio(0); \
  } while (0)

// pre-MFMA sync: barrier, drain own ds_reads, fence (rule #18)
#define SYNC_PRE() do { \
    __builtin_amdgcn_s_barrier(); \
    asm volatile("s_waitcnt lgkmcnt(0)" ::: "memory"); \
    __builtin_amdgcn_sched_barrier(0); \
  } while (0)
// post-MFMA sync: barrier, fence so next phase's memory ops can't hoist above
#define SYNC_POST() do { \
    __builtin_amdgcn_s_barrier(); \
    __builtin_amdgcn_sched_barrier(0); \
  } while (0)

#define VMCNT4() asm volatile("s_waitcnt vmcnt(4)" ::: "memory")

#define FOURPH(RB, WAB, KTA, WBB, KTB) do { \
    /* ph1 */ \
    LOAD_AV(RB, 0); LOAD_BV(bv0, RB, 0); \
    STAGE_HALF(A, bm, As_[WAB], kbeg + (KTA) * 64, 0); \
    SYNC_PRE(); MFMA_Q(0, bv0, 0); SYNC_POST(); \
    /* ph2 */ \
    LOAD_BV(bv1, RB, 1); \
    STAGE_HALF(A, bm, As_[WAB], kbeg + (KTA) * 64, 1); \
    SYNC_PRE(); MFMA_Q(0, bv1, 1); SYNC_POST(); \
    /* ph3 */ \
    LOAD_AV(RB, 1); \
    STAGE_HALF(Bt, bn, Bs_[WBB], kbeg + (KTB) * 64, 0); \
    SYNC_PRE(); MFMA_Q(1, bv0, 0); SYNC_POST(); \
    /* ph4 */ \
    STAGE_HALF(Bt, bn, Bs_[WBB], kbeg + (KTB) * 64, 1); \
    SYNC_PRE(); MFMA_Q(1, bv1, 1); VMCNT4(); SYNC_POST(); \
  } while (0)

template<int EPI>
__global__ __launch_bounds__(512, 2)
void gemm256(const bf16* __restrict__ A, const bf16* __restrict__ Bt,
             const float* __restrict__ b0, void* __restrict__ Cout,
             int M, int N, int ldk, int kchunk)
{
  __shared__ __align__(16) bf16 SmemAll[4][256 * 64];  // 128 KiB
  bf16* const As_[2] = {SmemAll[0], SmemAll[1]};
  bf16* const Bs_[2] = {SmemAll[2], SmemAll[3]};

  const int t = threadIdx.x;
  const int wave = t >> 6, lane = t & 63;
  const int lm = lane & 15, qd = lane >> 4;
  const int wm = (wave >> 2) * 128;       // 2 wave-rows of 128
  const int wnb = (wave & 3) * 64;        // 4 wave-cols of 64

  // XCD swizzle (grids here are 256 or 64 2D-blocks, % 8 == 0)
  const int nwg2d = gridDim.x * gridDim.y;
  const int cpx = nwg2d >> 3;
  const int lin2d = blockIdx.x + gridDim.x * blockIdx.y;
  const int swz = (lin2d & 7) * cpx + (lin2d >> 3);
  const int bm = (swz / gridDim.x) * 256, bn = (swz % gridDim.x) * 256;
  const int kbeg = blockIdx.z * kchunk;
  const int NT = kchunk >> 6;             // K-tiles per block (16)

  f32x4 acc[8][4] = {};
  bf16x8 av[4][2], bv0[2][2], bv1[2][2];

  // prologue: stage B(0), A(0), B(1); drain all but B(1)
  STAGE_HALF(Bt, bn, Bs_[0], kbeg, 0);
  STAGE_HALF(Bt, bn, Bs_[0], kbeg, 1);
  STAGE_HALF(A,  bm, As_[0], kbeg, 0);
  STAGE_HALF(A,  bm, As_[0], kbeg, 1);
  STAGE_HALF(Bt, bn, Bs_[1], kbeg + 64, 0);
  STAGE_HALF(Bt, bn, Bs_[1], kbeg + 64, 1);
  VMCNT4();
  SYNC_POST();

  for (int it = 0; it < NT / 2; ++it) {
    const int tb = 2 * it + 1;
    const int tc = (2 * it + 2) & (NT - 1);  // wraps on final iter: harmless
    const int td = (2 * it + 3) & (NT - 1);
    FOURPH(0, 1, tb, 0, tc);
    FOURPH(1, 0, tc, 1, td);
  }

  // ----------------- epilogue: per-wave 128x64 LDS bounce (Smem now dead)
  bf16* tw = &SmemAll[0][0] + wave * 8192;  // 128x64 bf16, XOR-swizzled
#pragma unroll
  for (int nt4 = 0; nt4 < 4; ++nt4) {
    const int n0 = bn + wnb + nt4 * 16 + qd * 4;
    f32x4 bsv = {0.f, 0.f, 0.f, 0.f};
    if (EPI == 2) bsv = *(const f32x4*)(b0 + n0);
#pragma unroll
    for (int mt8 = 0; mt8 < 8; ++mt8) {
      f32x4 v;
#pragma unroll
      for (int r = 0; r < 4; ++r) v[r] = acc[mt8][nt4][r] + bsv[r];
      bf16x4 o;
      if (EPI == 2) {
#pragma unroll
        for (int r = 0; r < 4; ++r) o[r] = (bf16)gelu_erf_f(v[r]);
      } else {
#pragma unroll
        for (int r = 0; r < 4; ++r) o[r] = (bf16)v[r];
      }
      *(bf16x4*)(tw + BSW(mt8 * 16 + lm, nt4 * 16 + qd * 4)) = o;
    }
  }
  // own-wave lgkmcnt orders ds_write->ds_read; per-wave private region.
  const int erow = lane >> 3, ech = lane & 7;
  bf16* dst = (bf16*)Cout +
              ((EPI == 1) ? (size_t)blockIdx.z * M * N : (size_t)0) +
              (size_t)(bm + wm) * N + (bn + wnb);
#pragma unroll
  for (int p = 0; p < 16; ++p) {
    const int row = p * 8 + erow;
    bf16x8 val = *(const bf16x8*)(tw + BSW(row, ech * 8));
    *(bf16x8*)(dst + (size_t)row * N + ech * 8) = val;
  }
}

// ---------------------------------------------------------------- flash attention
// Round-0 verified structure (NSPLIT=4, 2048 blocks).
__global__ __launch_bounds__(256)
void attn_kernel(const bf16* __restrict__ Q, const bf16* __restrict__ Kg,
                 const bf16* __restrict__ Vt, const int* __restrict__ mask,
                 bf16* __restrict__ Po, float* __restrict__ Lp)
{
  __shared__ __align__(16) bf16 Ks[64 * 64];   // [key][d], chunk-swizzled
  __shared__ __align__(16) bf16 Vs[64 * 64];   // [d][key], chunk-swizzled
  __shared__ float madd[64];

  const int t = threadIdx.x;
  const int wave = t >> 6, lane = t & 63;
  const int lm = lane & 15, qd = lane >> 4;

  const int lin = blockIdx.x;
  const int g = (lin & 7) * 16 + (lin >> 7);
  const int qblk = (lin >> 3) & 15;
  const int bh = g >> 2;
  const int split = g & 3;
  const int b = bh >> 4, h = bh & 15;
  const int q0 = qblk * 128 + wave * 32;
  const int kv_beg = split * (SEQ / NSPLIT);

  bf16x8 qf[2][2];
#pragma unroll
  for (int qt = 0; qt < 2; ++qt)
#pragma unroll
    for (int ks = 0; ks < 2; ++ks)
      qf[qt][ks] = *(const bf16x8*)(Q + (size_t)(b * SEQ + q0 + qt * 16 + lm) * HDIM +
                                    h * HD + ks * 32 + qd * 8);

  const bf16 onev = (bf16)1.0f;
  const bf16x4 ones = {onev, onev, onev, onev};
  f32x4 lacc[2] = {};      // l via MFMA: all entries = colsum for q=lm
  f32x4 oacc[2][4] = {};   // [qt][nt2] O^T: d = nt2*16+qd*4+r, q = lm

  const int srow = t >> 3, schk = t & 7;
  const float C = 0.1803368801f;  // log2(e)/8

  for (int kv0 = kv_beg; kv0 < kv_beg + SEQ / NSPLIT; kv0 += 64) {
#pragma unroll
    for (int r = 0; r < 2; ++r) {
      const int row = r * 32 + srow;
      const int g2 = schk ^ (row & 7);
      async_load16(Kg + (size_t)(b * SEQ + kv0 + row) * HDIM + h * HD + g2 * 8,
                   (bf16*)((char*)Ks + r * 4096 + t * 16));
      async_load16(Vt + (size_t)(bh * HD + row) * SEQ + kv0 + g2 * 8,
                   (bf16*)((char*)Vs + r * 4096 + t * 16));
    }
    if (t < 64) madd[t] = (mask[b * SEQ + kv0 + t] == 1) ? 0.f : -1.0e30f;
    __syncthreads();

    bf16x8 kf[2][4];
#pragma unroll
    for (int ks = 0; ks < 2; ++ks)
#pragma unroll
      for (int nt = 0; nt < 4; ++nt) {
        const int row = nt * 16 + lm;
        const int c = (ks * 4 + qd) ^ (row & 7);
        kf[ks][nt] = *(const bf16x8*)(Ks + row * 64 + c * 8);
      }

    bf16x4 pf[2][4];
#pragma unroll
    for (int qt = 0; qt < 2; ++qt) {
      f32x4 sacc[4] = {};
#pragma unroll
      for (int ks = 0; ks < 2; ++ks)
#pragma unroll
        for (int nt = 0; nt < 4; ++nt)
          sacc[nt] = __builtin_amdgcn_mfma_f32_16x16x32_bf16(kf[ks][nt], qf[qt][ks], sacc[nt], 0, 0, 0);
#pragma unroll
      for (int nt = 0; nt < 4; ++nt) {
        f32x4 ma = *(const f32x4*)(madd + nt * 16 + qd * 4);
#pragma unroll
        for (int r = 0; r < 4; ++r)
          pf[qt][nt][r] = (bf16)__builtin_amdgcn_exp2f(fmaf(sacc[nt][r], C, ma[r]));
        lacc[qt] = mfma16_bf16(ones, pf[qt][nt], lacc[qt]);
      }
    }

#pragma unroll
    for (int nt2 = 0; nt2 < 4; ++nt2) {
      const int row = nt2 * 16 + lm;
#pragma unroll
      for (int nt = 0; nt < 4; ++nt) {
        bf16x4 vf = *(const bf16x4*)(Vs + row * 64 +
                     (((nt * 2 + (qd >> 1)) ^ (row & 7)) * 8) + (qd & 1) * 4);
        oacc[0][nt2] = mfma16_bf16(vf, pf[0][nt], oacc[0][nt2]);
        oacc[1][nt2] = mfma16_bf16(vf, pf[1][nt], oacc[1][nt2]);
      }
    }
    __syncthreads();
  }

  bf16* po = Po + (size_t)(split * 32 + bh) * 64 * SEQ;
#pragma unroll
  for (int qt = 0; qt < 2; ++qt) {
#pragma unroll
    for (int nt2 = 0; nt2 < 4; ++nt2)
#pragma unroll
      for (int r = 0; r < 4; ++r)
        po[(size_t)(nt2 * 16 + qd * 4 + r) * SEQ + q0 + qt * 16 + lm] =
            (bf16)oacc[qt][nt2][r];
    if (qd == 0)
      Lp[(size_t)(split * 32 + bh) * SEQ + q0 + qt * 16 + lm] = lacc[qt][0];
  }
}

// ------------------------------- attn merge via LDS tile
__global__ __launch_bounds__(256)
void attn_merge(const bf16* __restrict__ Po, const float* __restrict__ Lp,
                bf16* __restrict__ Aout)
{
  __shared__ bf16 tile[64][80];
  __shared__ float linv[64];
  const int t = threadIdx.x;
  const int bh = blockIdx.y;
  const int b = bh >> 4, h = bh & 15;
  const int s0 = blockIdx.x * 64;

  if (t < 64) {
    float l = 0.f;
#pragma unroll
    for (int s = 0; s < NSPLIT; ++s)
      l += Lp[(size_t)(s * 32 + bh) * SEQ + s0 + t];
    linv[t] = 1.0f / l;
  }
  __syncthreads();

#pragma unroll
  for (int it = 0; it < 2; ++it) {
    const int d = (t >> 3) + 32 * it;
    const int sc = (t & 7) * 8;
    float acc[8] = {};
#pragma unroll
    for (int s = 0; s < NSPLIT; ++s) {
      bf16x8 v = *(const bf16x8*)(Po + ((size_t)(s * 32 + bh) * 64 + d) * SEQ + s0 + sc);
#pragma unroll
      for (int j = 0; j < 8; ++j) acc[j] += (float)v[j];
    }
#pragma unroll
    for (int j = 0; j < 8; ++j)
      tile[sc + j][d] = (bf16)(acc[j] * linv[sc + j]);
  }
  __syncthreads();

  const int tok = t >> 2, dc = (t & 3) * 16;
  bf16x8 o0 = *(const bf16x8*)&tile[tok][dc];
  bf16x8 o1 = *(const bf16x8*)&tile[tok][dc + 8];
  bf16* dst = Aout + (size_t)(b * SEQ + s0 + tok) * HDIM + h * HD + dc;
  *(bf16x8*)dst = o0;
  *(bf16x8*)(dst + 8) = o1;
}

// ------------------------------- layernorm over H=1024
template<int NP, int OUT_BF16>
__global__ __launch_bounds__(256)
void ln_sum(const bf16* __restrict__ p, const float* __restrict__ bias,
            const float* __restrict__ gamma, const float* __restrict__ beta,
            void* __restrict__ out)
{
  const int row = blockIdx.x;
  const int t = threadIdx.x;
  f32x4 v = {0.f, 0.f, 0.f, 0.f};
#pragma unroll
  for (int np = 0; np < NP; ++np) {
    bf16x4 u = *(const bf16x4*)(p + np * PSTRIDE + (size_t)row * HDIM + t * 4);
#pragma unroll
    for (int j = 0; j < 4; ++j) v[j] += (float)u[j];
  }
  f32x4 bv0 = *(const f32x4*)(bias + t * 4);
#pragma unroll
  for (int j = 0; j < 4; ++j) v[j] += bv0[j];

  float s = v[0] + v[1] + v[2] + v[3];
  float s2 = v[0] * v[0] + v[1] * v[1] + v[2] * v[2] + v[3] * v[3];
#pragma unroll
  for (int d = 1; d < 64; d <<= 1) { s += __shfl_xor(s, d, 64); s2 += __shfl_xor(s2, d, 64); }
  __shared__ float ss[4], ss2[4];
  const int wave = t >> 6, lane = t & 63;
  if (lane == 0) { ss[wave] = s; ss2[wave] = s2; }
  __syncthreads();
  s = ss[0] + ss[1] + ss[2] + ss[3];
  s2 = ss2[0] + ss2[1] + ss2[2] + ss2[3];
  const float mean = s * (1.0f / HDIM);
  const float var = s2 * (1.0f / HDIM) - mean * mean;
  const float rstd = rsqrtf(var + 1e-12f);
  f32x4 gv = *(const f32x4*)(gamma + t * 4);
  f32x4 bv = *(const f32x4*)(beta + t * 4);
  f32x4 y;
#pragma unroll
  for (int j = 0; j < 4; ++j) y[j] = gv[j] * (v[j] - mean) * rstd + bv[j];
  if (OUT_BF16) {
    bf16x4 o;
#pragma unroll
    for (int j = 0; j < 4; ++j) o[j] = (bf16)y[j];
    *(bf16x4*)((bf16*)out + (size_t)row * HDIM + t * 4) = o;
  } else {
    *(f32x4*)((float*)out + (size_t)row * HDIM + t * 4) = y;
  }
}

// ---------------------------------------------------------------- launch
extern "C" void kernel_launch(void* const* d_in, const int* in_sizes, int n_in,
                              void* d_out, int out_size, void* d_ws, size_t ws_size,
                              hipStream_t stream)
{
  const float* x    = (const float*)d_in[0];
  const int*   am   = (const int*)d_in[1];
  const float* Wq   = (const float*)d_in[2];
  const float* bq   = (const float*)d_in[3];
  const float* Wk   = (const float*)d_in[4];
  const float* bk   = (const float*)d_in[5];
  const float* Wv   = (const float*)d_in[6];
  const float* bv   = (const float*)d_in[7];
  const float* Wo   = (const float*)d_in[8];
  const float* bo   = (const float*)d_in[9];
  const float* ln1g = (const float*)d_in[10];
  const float* ln1b = (const float*)d_in[11];
  const float* W1   = (const float*)d_in[12];
  const float* b1   = (const float*)d_in[13];
  const float* W2   = (const float*)d_in[14];
  const float* b2   = (const float*)d_in[15];
  const float* ln2g = (const float*)d_in[16];
  const float* ln2b = (const float*)d_in[17];

  char* ws = (char*)d_ws;
  const size_t MB = 1ull << 20;
  bf16*  W1T  = (bf16*)(ws + 0 * MB);    // 8 MiB
  bf16*  W2T  = (bf16*)(ws + 8 * MB);    // 8 MiB
  bf16*  Xb   = (bf16*)(ws + 16 * MB);   // 8 MiB (dead after QKV)
  bf16*  QKVT = (bf16*)(ws + 24 * MB);   // 8 MiB (WoT = last quarter)
  bf16*  WoT  = QKVT + (size_t)3 * HDIM * HDIM;
  bf16*  Qb   = (bf16*)(ws + 33 * MB);   // Q(33-41), K(41-49), Vt(49-57)
  bf16*  Kb   = (bf16*)(ws + 41 * MB);
  bf16*  Vtb  = (bf16*)(ws + 49 * MB);
  bf16*  Po   = (bf16*)(ws + 57 * MB);   // 32 MiB attn O^T bf16 partials (57-89)
  float* Lp   = (float*)(ws + 89 * MB);  // 1 MiB l partials (4 splits)
  bf16*  Ab   = (bf16*)(ws + 16 * MB);   // merge out, reuse Xb
  bf16*  Pw   = (bf16*)(ws + 33 * MB);   // Wo bf16 partials 33-49 (Q/K dead)
  bf16*  L1   = (bf16*)(ws + 65 * MB);   // 8 MiB
  bf16*  F1   = (bf16*)(ws + 16 * MB);   // 32 MiB (16-48)
  bf16*  Pf   = (bf16*)(ws + 48 * MB);   // FFN2 bf16 partials 48-80

  prep_kernel<<<dim3(32, 32, 13), 256, 0, stream>>>(x, Wq, Wk, Wv, Wo, W1, W2,
                                                    Xb, QKVT, W1T, W2T);

  gemm_bt<3><<<dim3(3072 / 128, M_TOK / 128, 1), 256, 0, stream>>>(
      Xb, QKVT, bq, bk, bv, Qb, M_TOK, 3072, HDIM, HDIM);

  attn_kernel<<<dim3(2048, 1, 1), 256, 0, stream>>>(Qb, Kb, Vtb, am, Po, Lp);
  attn_merge<<<dim3(SEQ / 64, BATCH * NHEAD), 256, 0, stream>>>(Po, Lp, Ab);

  gemm_bt<1><<<dim3(HDIM / 128, M_TOK / 128, 2), 256, 0, stream>>>(
      Ab, WoT, nullptr, nullptr, nullptr, Pw, M_TOK, HDIM, HDIM, 512);
  ln_sum<2, 1><<<M_TOK, 256, 0, stream>>>(Pw, bo, ln1g, ln1b, L1);

  gemm256<2><<<dim3(FFDIM / 256, M_TOK / 256, 1), 512, 0, stream>>>(
      L1, W1T, b1, F1, M_TOK, FFDIM, HDIM, HDIM);

  gemm256<1><<<dim3(HDIM / 256, M_TOK / 256, 4), 512, 0, stream>>>(
      F1, W2T, nullptr, Pf, M_TOK, HDIM, FFDIM, 1024);
  ln_sum<4, 0><<<M_TOK, 256, 0, stream>>>(Pf, b2, ln2g, ln2b, (float*)d_out);
}

// Round 9
// 326.706 us; speedup vs baseline: 1.4458x; 1.0305x over previous
//
#include <hip/hip_runtime.h>
#include <hip/hip_bf16.h>
#include <math.h>

typedef __bf16 bf16;
typedef __attribute__((ext_vector_type(8))) __bf16 bf16x8;
typedef __attribute__((ext_vector_type(4))) __bf16 bf16x4;
typedef __attribute__((ext_vector_type(2))) __bf16 bf16x2;
typedef __attribute__((ext_vector_type(4))) float f32x4;
typedef __attribute__((ext_vector_type(4))) short short4v;

#define HDIM 1024
#define NHEAD 16
#define HD 64
#define FFDIM 4096
#define BATCH 2
#define SEQ 2048
#define M_TOK 4096  // BATCH*SEQ
#define NSPLIT 4
#define PSTRIDE ((size_t)M_TOK * HDIM)  // elements between split-K partials

static __device__ __forceinline__ void async_load16(const bf16* g, bf16* l) {
  __builtin_amdgcn_global_load_lds(
      (const __attribute__((address_space(1))) void*)g,
      (__attribute__((address_space(3))) void*)l, 16, 0, 0);
}

// 16x16x16 bf16 MFMA wrapper (attn uses it). Host pass has no amdgcn builtins.
static __device__ __forceinline__ f32x4 mfma16_bf16(bf16x4 a, bf16x4 b, f32x4 c) {
#if defined(__HIP_DEVICE_COMPILE__)
#if __has_builtin(__builtin_amdgcn_mfma_f32_16x16x16bf16_1k)
  return __builtin_amdgcn_mfma_f32_16x16x16bf16_1k(
      __builtin_bit_cast(short4v, a), __builtin_bit_cast(short4v, b), c, 0, 0, 0);
#else
  return __builtin_amdgcn_mfma_f32_16x16x16_bf16(a, b, c, 0, 0, 0);
#endif
#else
  return c;  // host pass: never executed
#endif
}

static __device__ __forceinline__ float gelu_erf_f(float x) {
  const float z = x * 0.70710678118f;
  const float az = fabsf(z);
  const float tt = __builtin_amdgcn_rcpf(fmaf(az, 0.3275911f, 1.0f));
  const float poly = tt * fmaf(tt, fmaf(tt, fmaf(tt, fmaf(tt, 1.061405429f,
                     -1.453152027f), 1.421413741f), -0.284496736f), 0.254829592f);
  const float e = __builtin_amdgcn_exp2f(az * az * -1.4426950408889634f);
  float erfv = 1.0f - poly * e;
  erfv = (z < 0.f) ? -erfv : erfv;
  return 0.5f * x * (1.0f + erfv);
}

// ---------------------------------------------------------------- prep: all transposes + x cast
__global__ __launch_bounds__(256)
void prep_kernel(const float* __restrict__ x,
                 const float* __restrict__ Wq, const float* __restrict__ Wk,
                 const float* __restrict__ Wv, const float* __restrict__ Wo,
                 const float* __restrict__ W1, const float* __restrict__ W2,
                 bf16* __restrict__ Xb, bf16* __restrict__ QKVT,
                 bf16* __restrict__ W1T, bf16* __restrict__ W2T)
{
  const int z = blockIdx.z;
  const int t = threadIdx.x;
  if (z == 12) {
    const size_t base = ((size_t)(blockIdx.y * 32 + blockIdx.x)) * 4096;
#pragma unroll
    for (int j = 0; j < 4; ++j) {
      const size_t i = base + j * 1024 + t * 4;
      f32x4 v = *(const f32x4*)(x + i);
      bf16x4 o;
#pragma unroll
      for (int k = 0; k < 4; ++k) o[k] = (bf16)v[k];
      *(bf16x4*)(Xb + i) = o;
    }
    return;
  }
  const float* ps; bf16* pd; int sld, dld;
  if (z < 4) {
    ps = (z == 0) ? Wq : (z == 1) ? Wk : (z == 2) ? Wv : Wo;
    pd = QKVT + (size_t)z * HDIM * HDIM; sld = 1024; dld = 1024;
  } else if (z < 8) {
    const int c = z - 4;
    ps = W1 + c * 1024; sld = 4096;
    pd = W1T + (size_t)c * 1024 * 1024; dld = 1024;
  } else {
    const int c = z - 8;
    ps = W2 + (size_t)c * 1024 * 1024; sld = 1024;
    pd = W2T + c * 1024; dld = 4096;
  }
  __shared__ float tile[32][33];
  const int tx = t & 31, ty = t >> 5;
  const int c0 = blockIdx.x * 32, r0 = blockIdx.y * 32;
#pragma unroll
  for (int i = 0; i < 32; i += 8)
    tile[ty + i][tx] = ps[(size_t)(r0 + ty + i) * sld + c0 + tx];
  __syncthreads();
  const int rr0 = (t & 15) * 2;
  const int ccb = t >> 4;  // 0..15
#pragma unroll
  for (int i = 0; i < 2; ++i) {
    const int cc = ccb + 16 * i;
    bf16x2 v = {(bf16)tile[rr0][cc], (bf16)tile[rr0 + 1][cc]};
    *(bf16x2*)(pd + (size_t)(c0 + cc) * dld + r0 + rr0) = v;
  }
}

// ---------------------------------------------------------------- GEMM 128^2 (Wo)
// Verified 2-barrier structure + swizzled LDS-bounce epilogue + XCD swizzle.
#define BSW(R, C) ((R) * 64 + ((C) ^ (((R) & 7) << 3)))
#define BSW128(R, C) ((R) * 128 + ((C) ^ (((R) & 7) << 3)))

template<int EPI>
__global__ __launch_bounds__(256)
void gemm_bt(const bf16* __restrict__ A, const bf16* __restrict__ Bt,
             const float* __restrict__ b0, const float* __restrict__ b1p,
             const float* __restrict__ b2p, void* __restrict__ Cout,
             int M, int N, int ldk, int kchunk)
{
  __shared__ __align__(16) bf16 Smem[2][128 * 64];  // As | Bs, contiguous 32KiB
  bf16* As = Smem[0];
  bf16* Bs = Smem[1];
  const int t = threadIdx.x;
  const int wave = t >> 6, lane = t & 63;
  const int lm = lane & 15, qd = lane >> 4;
  const int wm = (wave >> 1) * 64, wn = (wave & 1) * 64;

  const int nwg2d = gridDim.x * gridDim.y;
  const int cpx = nwg2d >> 3;
  const int lin2d = blockIdx.x + gridDim.x * blockIdx.y;
  const int swz = (lin2d & 7) * cpx + (lin2d >> 3);
  const int bxs = swz % gridDim.x;
  const int bys = swz / gridDim.x;
  const int bm = bys * 128, bn = bxs * 128;
  const int kbeg = blockIdx.z * kchunk;

  f32x4 acc[4][4] = {};
  const int srow = t >> 3;
  const int schk = t & 7;

  for (int k0 = kbeg; k0 < kbeg + kchunk; k0 += 64) {
#pragma unroll
    for (int r = 0; r < 4; ++r) {
      const int row = r * 32 + srow;
      const int chunk = schk ^ (row & 7);
      async_load16(A + (size_t)(bm + row) * ldk + (k0 + chunk * 8),
                   (bf16*)((char*)As + r * 4096 + t * 16));
    }
#pragma unroll
    for (int r = 0; r < 4; ++r) {
      const int row = r * 32 + srow;
      const int chunk = schk ^ (row & 7);
      async_load16(Bt + (size_t)(bn + row) * ldk + (k0 + chunk * 8),
                   (bf16*)((char*)Bs + r * 4096 + t * 16));
    }
    __syncthreads();
#pragma unroll
    for (int ks = 0; ks < 2; ++ks) {
      bf16x8 av[4], bv[4];
#pragma unroll
      for (int mt = 0; mt < 4; ++mt) {
        const int row = wm + mt * 16 + lm;
        const int chunk = (ks * 4 + qd) ^ (row & 7);
        av[mt] = *(const bf16x8*)(As + row * 64 + chunk * 8);
      }
#pragma unroll
      for (int nt = 0; nt < 4; ++nt) {
        const int row = wn + nt * 16 + lm;
        const int chunk = (ks * 4 + qd) ^ (row & 7);
        bv[nt] = *(const bf16x8*)(Bs + row * 64 + chunk * 8);
      }
#pragma unroll
      for (int mt = 0; mt < 4; ++mt)
#pragma unroll
        for (int nt = 0; nt < 4; ++nt)
          acc[mt][nt] = __builtin_amdgcn_mfma_f32_16x16x32_bf16(bv[nt], av[mt], acc[mt][nt], 0, 0, 0);
    }
    __syncthreads();
  }

  bf16* tw = &Smem[0][0] + wave * 4096;  // 64x64 bf16 tile, XOR-swizzled
  const bool vt = (EPI == 3) && ((bn + wn) >= 2 * HDIM);

#pragma unroll
  for (int nt = 0; nt < 4; ++nt) {
    const int n0 = bn + wn + nt * 16 + qd * 4;
    f32x4 bsv = {0.f, 0.f, 0.f, 0.f};
    if (EPI == 2) bsv = *(const f32x4*)(b0 + n0);
    if (EPI == 3) {
      const int sect = n0 >> 10, c = n0 & 1023;
      const float* bp = (sect == 0) ? b0 : (sect == 1) ? b1p : b2p;
      bsv = *(const f32x4*)(bp + c);
    }
#pragma unroll
    for (int mt = 0; mt < 4; ++mt) {
      f32x4 v;
#pragma unroll
      for (int r = 0; r < 4; ++r) v[r] = acc[mt][nt][r] + bsv[r];
      bf16x4 o;
      if (EPI == 2) {
#pragma unroll
        for (int r = 0; r < 4; ++r) o[r] = (bf16)gelu_erf_f(v[r]);
      } else {
#pragma unroll
        for (int r = 0; r < 4; ++r) o[r] = (bf16)v[r];
      }
      if (!vt) {
        *(bf16x4*)(tw + BSW(mt * 16 + lm, nt * 16 + qd * 4)) = o;
      } else {
#pragma unroll
        for (int r = 0; r < 4; ++r)
          tw[BSW(nt * 16 + qd * 4 + r, mt * 16 + lm)] = o[r];
      }
    }
  }
  const int erow = lane >> 3, ech = lane & 7;
  if (EPI == 1) {
    bf16* dst = (bf16*)Cout + (size_t)blockIdx.z * M * N +
                (size_t)(bm + wm) * N + (bn + wn);
#pragma unroll
    for (int p = 0; p < 8; ++p) {
      const int row = p * 8 + erow;
      bf16x8 val = *(const bf16x8*)(tw + BSW(row, ech * 8));
      *(bf16x8*)(dst + (size_t)row * N + ech * 8) = val;
    }
  } else if (EPI == 2) {
    bf16* dst = (bf16*)Cout + (size_t)(bm + wm) * N + (bn + wn);
#pragma unroll
    for (int p = 0; p < 8; ++p) {
      const int row = p * 8 + erow;
      bf16x8 val = *(const bf16x8*)(tw + BSW(row, ech * 8));
      *(bf16x8*)(dst + (size_t)row * N + ech * 8) = val;
    }
  } else {
    bf16* base = (bf16*)Cout;
    const int sect = (bn + wn) >> 10;
    if (!vt) {
      bf16* dst = base + (size_t)sect * M_TOK * HDIM +
                  (size_t)(bm + wm) * HDIM + ((bn + wn) & 1023);
#pragma unroll
      for (int p = 0; p < 8; ++p) {
        const int row = p * 8 + erow;
        bf16x8 val = *(const bf16x8*)(tw + BSW(row, ech * 8));
        *(bf16x8*)(dst + (size_t)row * HDIM + ech * 8) = val;
      }
    } else {
      const int c0 = (bn + wn) & 1023;
      const int hh = c0 >> 6;
      const int bb = (bm + wm) >> 11, ss0 = (bm + wm) & 2047;
      bf16* dst = base + (size_t)2 * M_TOK * HDIM +
                  (size_t)((bb * NHEAD + hh) * HD) * SEQ + ss0;
#pragma unroll
      for (int p = 0; p < 8; ++p) {
        const int row = p * 8 + erow;  // d within head
        bf16x8 val = *(const bf16x8*)(tw + BSW(row, ech * 8));
        *(bf16x8*)(dst + (size_t)row * SEQ + ech * 8) = val;
      }
    }
  }
}

// ---------------------------------------------------------------- GEMM 256^2 8-phase (QKV, FFN1, FFN2)
// Minimal-fence 8-phase schedule (R8: beat gemm_bt on FFN1/FFN2).
// R9: + EPI3 (QKV fused epilogue). Per-wave n-block is 64-aligned within a
// 1024-aligned section -> sect/vt uniform per wave. V section uses a
// transposed 64x128 bounce tile (BSW128) so Vt stores run 256B-contiguous
// along s; Q/K use the normal 128x64 tile with sect-based dst.

#define STAGE_Q(OP, BASEMN, LDSB, KOFF, Q) do { \
    const int rr_ = (Q) * 64 + (t >> 3); \
    const int gc_ = (t & 7) ^ (rr_ & 7); \
    async_load16((OP) + (size_t)((BASEMN) + rr_) * ldk + (KOFF) + gc_ * 8, \
                 (LDSB) + (Q) * 4096 + t * 8); \
  } while (0)

#define STAGE_HALF(OP, BASEMN, LDSB, KOFF, H) do { \
    STAGE_Q(OP, BASEMN, LDSB, KOFF, 2 * (H)); \
    STAGE_Q(OP, BASEMN, LDSB, KOFF, 2 * (H) + 1); \
  } while (0)

#define LOAD_AV(BUF, MH) do { \
    _Pragma("unroll") \
    for (int mt_ = 0; mt_ < 4; ++mt_) { \
      const int row_ = wm + (MH) * 64 + mt_ * 16 + lm; \
      _Pragma("unroll") \
      for (int ks_ = 0; ks_ < 2; ++ks_) { \
        const int c_ = (ks_ * 4 + qd) ^ (row_ & 7); \
        av[mt_][ks_] = *(const bf16x8*)(As_[BUF] + row_ * 64 + c_ * 8); \
      } \
    } \
  } while (0)

#define LOAD_BV(DST, BUF, NH) do { \
    _Pragma("unroll") \
    for (int nt_ = 0; nt_ < 2; ++nt_) { \
      const int row_ = wnb + (NH) * 32 + nt_ * 16 + lm; \
      _Pragma("unroll") \
      for (int ks_ = 0; ks_ < 2; ++ks_) { \
        const int c_ = (ks_ * 4 + qd) ^ (row_ & 7); \
        DST[nt_][ks_] = *(const bf16x8*)(Bs_[BUF] + row_ * 64 + c_ * 8); \
      } \
    } \
  } while (0)

#define MFMA_Q(MH, BV, NH) do { \
    __builtin_amdgcn_s_setprio(1); \
    _Pragma("unroll") \
    for (int mt_ = 0; mt_ < 4; ++mt_) \
      _Pragma("unroll") \
      for (int nt_ = 0; nt_ < 2; ++nt_) \
        _Pragma("unroll") \
        for (int ks_ = 0; ks_ < 2; ++ks_) \
          acc[(MH) * 4 + mt_][(NH) * 2 + nt_] = \
              __builtin_amdgcn_mfma_f32_16x16x32_bf16( \
                  BV[nt_][ks_], av[mt_][ks_], \
                  acc[(MH) * 4 + mt_][(NH) * 2 + nt_], 0, 0, 0); \
    __builtin_amdgcn_s_setprio(0); \
  } while (0)

// pre-MFMA sync: barrier, drain own ds_reads, fence (rule #18)
#define SYNC_PRE() do { \
    __builtin_amdgcn_s_barrier(); \
    asm volatile("s_waitcnt lgkmcnt(0)" ::: "memory"); \
    __builtin_amdgcn_sched_barrier(0); \
  } while (0)
// post-MFMA sync: barrier, fence so next phase's memory ops can't hoist above
#define SYNC_POST() do { \
    __builtin_amdgcn_s_barrier(); \
    __builtin_amdgcn_sched_barrier(0); \
  } while (0)

#define VMCNT4() asm volatile("s_waitcnt vmcnt(4)" ::: "memory")

#define FOURPH(RB, WAB, KTA, WBB, KTB) do { \
    /* ph1 */ \
    LOAD_AV(RB, 0); LOAD_BV(bv0, RB, 0); \
    STAGE_HALF(A, bm, As_[WAB], kbeg + (KTA) * 64, 0); \
    SYNC_PRE(); MFMA_Q(0, bv0, 0); SYNC_POST(); \
    /* ph2 */ \
    LOAD_BV(bv1, RB, 1); \
    STAGE_HALF(A, bm, As_[WAB], kbeg + (KTA) * 64, 1); \
    SYNC_PRE(); MFMA_Q(0, bv1, 1); SYNC_POST(); \
    /* ph3 */ \
    LOAD_AV(RB, 1); \
    STAGE_HALF(Bt, bn, Bs_[WBB], kbeg + (KTB) * 64, 0); \
    SYNC_PRE(); MFMA_Q(1, bv0, 0); SYNC_POST(); \
    /* ph4 */ \
    STAGE_HALF(Bt, bn, Bs_[WBB], kbeg + (KTB) * 64, 1); \
    SYNC_PRE(); MFMA_Q(1, bv1, 1); VMCNT4(); SYNC_POST(); \
  } while (0)

template<int EPI>
__global__ __launch_bounds__(512, 2)
void gemm256(const bf16* __restrict__ A, const bf16* __restrict__ Bt,
             const float* __restrict__ b0, const float* __restrict__ b1p,
             const float* __restrict__ b2p, void* __restrict__ Cout,
             int M, int N, int ldk, int kchunk)
{
  __shared__ __align__(16) bf16 SmemAll[4][256 * 64];  // 128 KiB
  bf16* const As_[2] = {SmemAll[0], SmemAll[1]};
  bf16* const Bs_[2] = {SmemAll[2], SmemAll[3]};

  const int t = threadIdx.x;
  const int wave = t >> 6, lane = t & 63;
  const int lm = lane & 15, qd = lane >> 4;
  const int wm = (wave >> 2) * 128;       // 2 wave-rows of 128
  const int wnb = (wave & 3) * 64;        // 4 wave-cols of 64

  // XCD swizzle (grids here: 192 / 256 / 64 2D-blocks, all % 8 == 0)
  const int nwg2d = gridDim.x * gridDim.y;
  const int cpx = nwg2d >> 3;
  const int lin2d = blockIdx.x + gridDim.x * blockIdx.y;
  const int swz = (lin2d & 7) * cpx + (lin2d >> 3);
  const int bm = (swz / gridDim.x) * 256, bn = (swz % gridDim.x) * 256;
  const int kbeg = blockIdx.z * kchunk;
  const int NT = kchunk >> 6;             // K-tiles per block (16)

  f32x4 acc[8][4] = {};
  bf16x8 av[4][2], bv0[2][2], bv1[2][2];

  // prologue: stage B(0), A(0), B(1); drain all but B(1)
  STAGE_HALF(Bt, bn, Bs_[0], kbeg, 0);
  STAGE_HALF(Bt, bn, Bs_[0], kbeg, 1);
  STAGE_HALF(A,  bm, As_[0], kbeg, 0);
  STAGE_HALF(A,  bm, As_[0], kbeg, 1);
  STAGE_HALF(Bt, bn, Bs_[1], kbeg + 64, 0);
  STAGE_HALF(Bt, bn, Bs_[1], kbeg + 64, 1);
  VMCNT4();
  SYNC_POST();

  for (int it = 0; it < NT / 2; ++it) {
    const int tb = 2 * it + 1;
    const int tc = (2 * it + 2) & (NT - 1);  // wraps on final iter: harmless
    const int td = (2 * it + 3) & (NT - 1);
    FOURPH(0, 1, tb, 0, tc);
    FOURPH(1, 0, tc, 1, td);
  }

  // ----------------- epilogue: per-wave LDS bounce (Smem now dead)
  bf16* tw = &SmemAll[0][0] + wave * 8192;  // 16 KiB per wave
  const bool vt = (EPI == 3) && ((bn + wnb) >= 2 * HDIM);  // uniform per wave

#pragma unroll
  for (int nt4 = 0; nt4 < 4; ++nt4) {
    const int n0 = bn + wnb + nt4 * 16 + qd * 4;
    f32x4 bsv = {0.f, 0.f, 0.f, 0.f};
    if (EPI == 2) bsv = *(const f32x4*)(b0 + n0);
    if (EPI == 3) {
      const int sect = n0 >> 10, c = n0 & 1023;
      const float* bp = (sect == 0) ? b0 : (sect == 1) ? b1p : b2p;
      bsv = *(const f32x4*)(bp + c);
    }
#pragma unroll
    for (int mt8 = 0; mt8 < 8; ++mt8) {
      f32x4 v;
#pragma unroll
      for (int r = 0; r < 4; ++r) v[r] = acc[mt8][nt4][r] + bsv[r];
      bf16x4 o;
      if (EPI == 2) {
#pragma unroll
        for (int r = 0; r < 4; ++r) o[r] = (bf16)gelu_erf_f(v[r]);
      } else {
#pragma unroll
        for (int r = 0; r < 4; ++r) o[r] = (bf16)v[r];
      }
      if (!vt) {
        // [128 m][64 n] tile
        *(bf16x4*)(tw + BSW(mt8 * 16 + lm, nt4 * 16 + qd * 4)) = o;
      } else {
        // transposed [64 d][128 s] tile
#pragma unroll
        for (int r = 0; r < 4; ++r)
          tw[BSW128(nt4 * 16 + qd * 4 + r, mt8 * 16 + lm)] = o[r];
      }
    }
  }
  // own-wave lgkmcnt orders ds_write->ds_read; per-wave private region.
  const int erow = lane >> 3, ech = lane & 7;
  if (EPI != 3) {
    bf16* dst = (bf16*)Cout +
                ((EPI == 1) ? (size_t)blockIdx.z * M * N : (size_t)0) +
                (size_t)(bm + wm) * N + (bn + wnb);
#pragma unroll
    for (int p = 0; p < 16; ++p) {
      const int row = p * 8 + erow;
      bf16x8 val = *(const bf16x8*)(tw + BSW(row, ech * 8));
      *(bf16x8*)(dst + (size_t)row * N + ech * 8) = val;
    }
  } else {
    bf16* base = (bf16*)Cout;
    const int sect = (bn + wnb) >> 10;
    const int c0 = (bn + wnb) & 1023;
    if (!vt) {
      bf16* dst = base + (size_t)sect * M_TOK * HDIM +
                  (size_t)(bm + wm) * HDIM + c0;
#pragma unroll
      for (int p = 0; p < 16; ++p) {
        const int row = p * 8 + erow;
        bf16x8 val = *(const bf16x8*)(tw + BSW(row, ech * 8));
        *(bf16x8*)(dst + (size_t)row * HDIM + ech * 8) = val;
      }
    } else {
      // V: tile is [64 d][128 s]; store d rows, 256B contiguous along s
      const int hh = c0 >> 6;
      const int bb = (bm + wm) >> 11, ss0 = (bm + wm) & 2047;
      bf16* dst = base + (size_t)2 * M_TOK * HDIM +
                  (size_t)((bb * NHEAD + hh) * HD) * SEQ + ss0;
#pragma unroll
      for (int p = 0; p < 16; ++p) {
        const int row = p * 4 + qd;        // d 0..63
        const int cc = lm * 8;             // s-chunk
        bf16x8 val = *(const bf16x8*)(tw + BSW128(row, cc));
        *(bf16x8*)(dst + (size_t)row * SEQ + cc) = val;
      }
    }
  }
}

// ---------------------------------------------------------------- flash attention
// Round-0 verified structure (NSPLIT=4, 2048 blocks).
__global__ __launch_bounds__(256)
void attn_kernel(const bf16* __restrict__ Q, const bf16* __restrict__ Kg,
                 const bf16* __restrict__ Vt, const int* __restrict__ mask,
                 bf16* __restrict__ Po, float* __restrict__ Lp)
{
  __shared__ __align__(16) bf16 Ks[64 * 64];   // [key][d], chunk-swizzled
  __shared__ __align__(16) bf16 Vs[64 * 64];   // [d][key], chunk-swizzled
  __shared__ float madd[64];

  const int t = threadIdx.x;
  const int wave = t >> 6, lane = t & 63;
  const int lm = lane & 15, qd = lane >> 4;

  const int lin = blockIdx.x;
  const int g = (lin & 7) * 16 + (lin >> 7);
  const int qblk = (lin >> 3) & 15;
  const int bh = g >> 2;
  const int split = g & 3;
  const int b = bh >> 4, h = bh & 15;
  const int q0 = qblk * 128 + wave * 32;
  const int kv_beg = split * (SEQ / NSPLIT);

  bf16x8 qf[2][2];
#pragma unroll
  for (int qt = 0; qt < 2; ++qt)
#pragma unroll
    for (int ks = 0; ks < 2; ++ks)
      qf[qt][ks] = *(const bf16x8*)(Q + (size_t)(b * SEQ + q0 + qt * 16 + lm) * HDIM +
                                    h * HD + ks * 32 + qd * 8);

  const bf16 onev = (bf16)1.0f;
  const bf16x4 ones = {onev, onev, onev, onev};
  f32x4 lacc[2] = {};      // l via MFMA: all entries = colsum for q=lm
  f32x4 oacc[2][4] = {};   // [qt][nt2] O^T: d = nt2*16+qd*4+r, q = lm

  const int srow = t >> 3, schk = t & 7;
  const float C = 0.1803368801f;  // log2(e)/8

  for (int kv0 = kv_beg; kv0 < kv_beg + SEQ / NSPLIT; kv0 += 64) {
#pragma unroll
    for (int r = 0; r < 2; ++r) {
      const int row = r * 32 + srow;
      const int g2 = schk ^ (row & 7);
      async_load16(Kg + (size_t)(b * SEQ + kv0 + row) * HDIM + h * HD + g2 * 8,
                   (bf16*)((char*)Ks + r * 4096 + t * 16));
      async_load16(Vt + (size_t)(bh * HD + row) * SEQ + kv0 + g2 * 8,
                   (bf16*)((char*)Vs + r * 4096 + t * 16));
    }
    if (t < 64) madd[t] = (mask[b * SEQ + kv0 + t] == 1) ? 0.f : -1.0e30f;
    __syncthreads();

    bf16x8 kf[2][4];
#pragma unroll
    for (int ks = 0; ks < 2; ++ks)
#pragma unroll
      for (int nt = 0; nt < 4; ++nt) {
        const int row = nt * 16 + lm;
        const int c = (ks * 4 + qd) ^ (row & 7);
        kf[ks][nt] = *(const bf16x8*)(Ks + row * 64 + c * 8);
      }

    bf16x4 pf[2][4];
#pragma unroll
    for (int qt = 0; qt < 2; ++qt) {
      f32x4 sacc[4] = {};
#pragma unroll
      for (int ks = 0; ks < 2; ++ks)
#pragma unroll
        for (int nt = 0; nt < 4; ++nt)
          sacc[nt] = __builtin_amdgcn_mfma_f32_16x16x32_bf16(kf[ks][nt], qf[qt][ks], sacc[nt], 0, 0, 0);
#pragma unroll
      for (int nt = 0; nt < 4; ++nt) {
        f32x4 ma = *(const f32x4*)(madd + nt * 16 + qd * 4);
#pragma unroll
        for (int r = 0; r < 4; ++r)
          pf[qt][nt][r] = (bf16)__builtin_amdgcn_exp2f(fmaf(sacc[nt][r], C, ma[r]));
        lacc[qt] = mfma16_bf16(ones, pf[qt][nt], lacc[qt]);
      }
    }

#pragma unroll
    for (int nt2 = 0; nt2 < 4; ++nt2) {
      const int row = nt2 * 16 + lm;
#pragma unroll
      for (int nt = 0; nt < 4; ++nt) {
        bf16x4 vf = *(const bf16x4*)(Vs + row * 64 +
                     (((nt * 2 + (qd >> 1)) ^ (row & 7)) * 8) + (qd & 1) * 4);
        oacc[0][nt2] = mfma16_bf16(vf, pf[0][nt], oacc[0][nt2]);
        oacc[1][nt2] = mfma16_bf16(vf, pf[1][nt], oacc[1][nt2]);
      }
    }
    __syncthreads();
  }

  bf16* po = Po + (size_t)(split * 32 + bh) * 64 * SEQ;
#pragma unroll
  for (int qt = 0; qt < 2; ++qt) {
#pragma unroll
    for (int nt2 = 0; nt2 < 4; ++nt2)
#pragma unroll
      for (int r = 0; r < 4; ++r)
        po[(size_t)(nt2 * 16 + qd * 4 + r) * SEQ + q0 + qt * 16 + lm] =
            (bf16)oacc[qt][nt2][r];
    if (qd == 0)
      Lp[(size_t)(split * 32 + bh) * SEQ + q0 + qt * 16 + lm] = lacc[qt][0];
  }
}

// ------------------------------- attn merge via LDS tile
__global__ __launch_bounds__(256)
void attn_merge(const bf16* __restrict__ Po, const float* __restrict__ Lp,
                bf16* __restrict__ Aout)
{
  __shared__ bf16 tile[64][80];
  __shared__ float linv[64];
  const int t = threadIdx.x;
  const int bh = blockIdx.y;
  const int b = bh >> 4, h = bh & 15;
  const int s0 = blockIdx.x * 64;

  if (t < 64) {
    float l = 0.f;
#pragma unroll
    for (int s = 0; s < NSPLIT; ++s)
      l += Lp[(size_t)(s * 32 + bh) * SEQ + s0 + t];
    linv[t] = 1.0f / l;
  }
  __syncthreads();

#pragma unroll
  for (int it = 0; it < 2; ++it) {
    const int d = (t >> 3) + 32 * it;
    const int sc = (t & 7) * 8;
    float acc[8] = {};
#pragma unroll
    for (int s = 0; s < NSPLIT; ++s) {
      bf16x8 v = *(const bf16x8*)(Po + ((size_t)(s * 32 + bh) * 64 + d) * SEQ + s0 + sc);
#pragma unroll
      for (int j = 0; j < 8; ++j) acc[j] += (float)v[j];
    }
#pragma unroll
    for (int j = 0; j < 8; ++j)
      tile[sc + j][d] = (bf16)(acc[j] * linv[sc + j]);
  }
  __syncthreads();

  const int tok = t >> 2, dc = (t & 3) * 16;
  bf16x8 o0 = *(const bf16x8*)&tile[tok][dc];
  bf16x8 o1 = *(const bf16x8*)&tile[tok][dc + 8];
  bf16* dst = Aout + (size_t)(b * SEQ + s0 + tok) * HDIM + h * HD + dc;
  *(bf16x8*)dst = o0;
  *(bf16x8*)(dst + 8) = o1;
}

// ------------------------------- layernorm over H=1024
template<int NP, int OUT_BF16>
__global__ __launch_bounds__(256)
void ln_sum(const bf16* __restrict__ p, const float* __restrict__ bias,
            const float* __restrict__ gamma, const float* __restrict__ beta,
            void* __restrict__ out)
{
  const int row = blockIdx.x;
  const int t = threadIdx.x;
  f32x4 v = {0.f, 0.f, 0.f, 0.f};
#pragma unroll
  for (int np = 0; np < NP; ++np) {
    bf16x4 u = *(const bf16x4*)(p + np * PSTRIDE + (size_t)row * HDIM + t * 4);
#pragma unroll
    for (int j = 0; j < 4; ++j) v[j] += (float)u[j];
  }
  f32x4 bv0 = *(const f32x4*)(bias + t * 4);
#pragma unroll
  for (int j = 0; j < 4; ++j) v[j] += bv0[j];

  float s = v[0] + v[1] + v[2] + v[3];
  float s2 = v[0] * v[0] + v[1] * v[1] + v[2] * v[2] + v[3] * v[3];
#pragma unroll
  for (int d = 1; d < 64; d <<= 1) { s += __shfl_xor(s, d, 64); s2 += __shfl_xor(s2, d, 64); }
  __shared__ float ss[4], ss2[4];
  const int wave = t >> 6, lane = t & 63;
  if (lane == 0) { ss[wave] = s; ss2[wave] = s2; }
  __syncthreads();
  s = ss[0] + ss[1] + ss[2] + ss[3];
  s2 = ss2[0] + ss2[1] + ss2[2] + ss2[3];
  const float mean = s * (1.0f / HDIM);
  const float var = s2 * (1.0f / HDIM) - mean * mean;
  const float rstd = rsqrtf(var + 1e-12f);
  f32x4 gv = *(const f32x4*)(gamma + t * 4);
  f32x4 bv = *(const f32x4*)(beta + t * 4);
  f32x4 y;
#pragma unroll
  for (int j = 0; j < 4; ++j) y[j] = gv[j] * (v[j] - mean) * rstd + bv[j];
  if (OUT_BF16) {
    bf16x4 o;
#pragma unroll
    for (int j = 0; j < 4; ++j) o[j] = (bf16)y[j];
    *(bf16x4*)((bf16*)out + (size_t)row * HDIM + t * 4) = o;
  } else {
    *(f32x4*)((float*)out + (size_t)row * HDIM + t * 4) = y;
  }
}

// ---------------------------------------------------------------- launch
extern "C" void kernel_launch(void* const* d_in, const int* in_sizes, int n_in,
                              void* d_out, int out_size, void* d_ws, size_t ws_size,
                              hipStream_t stream)
{
  const float* x    = (const float*)d_in[0];
  const int*   am   = (const int*)d_in[1];
  const float* Wq   = (const float*)d_in[2];
  const float* bq   = (const float*)d_in[3];
  const float* Wk   = (const float*)d_in[4];
  const float* bk   = (const float*)d_in[5];
  const float* Wv   = (const float*)d_in[6];
  const float* bv   = (const float*)d_in[7];
  const float* Wo   = (const float*)d_in[8];
  const float* bo   = (const float*)d_in[9];
  const float* ln1g = (const float*)d_in[10];
  const float* ln1b = (const float*)d_in[11];
  const float* W1   = (const float*)d_in[12];
  const float* b1   = (const float*)d_in[13];
  const float* W2   = (const float*)d_in[14];
  const float* b2   = (const float*)d_in[15];
  const float* ln2g = (const float*)d_in[16];
  const float* ln2b = (const float*)d_in[17];

  char* ws = (char*)d_ws;
  const size_t MB = 1ull << 20;
  bf16*  W1T  = (bf16*)(ws + 0 * MB);    // 8 MiB
  bf16*  W2T  = (bf16*)(ws + 8 * MB);    // 8 MiB
  bf16*  Xb   = (bf16*)(ws + 16 * MB);   // 8 MiB (dead after QKV)
  bf16*  QKVT = (bf16*)(ws + 24 * MB);   // 8 MiB (WoT = last quarter)
  bf16*  WoT  = QKVT + (size_t)3 * HDIM * HDIM;
  bf16*  Qb   = (bf16*)(ws + 33 * MB);   // Q(33-41), K(41-49), Vt(49-57)
  bf16*  Kb   = (bf16*)(ws + 41 * MB);
  bf16*  Vtb  = (bf16*)(ws + 49 * MB);
  bf16*  Po   = (bf16*)(ws + 57 * MB);   // 32 MiB attn O^T bf16 partials (57-89)
  float* Lp   = (float*)(ws + 89 * MB);  // 1 MiB l partials (4 splits)
  bf16*  Ab   = (bf16*)(ws + 16 * MB);   // merge out, reuse Xb
  bf16*  Pw   = (bf16*)(ws + 33 * MB);   // Wo bf16 partials 33-49 (Q/K dead)
  bf16*  L1   = (bf16*)(ws + 65 * MB);   // 8 MiB
  bf16*  F1   = (bf16*)(ws + 16 * MB);   // 32 MiB (16-48)
  bf16*  Pf   = (bf16*)(ws + 48 * MB);   // FFN2 bf16 partials 48-80

  prep_kernel<<<dim3(32, 32, 13), 256, 0, stream>>>(x, Wq, Wk, Wv, Wo, W1, W2,
                                                    Xb, QKVT, W1T, W2T);

  gemm256<3><<<dim3(3072 / 256, M_TOK / 256, 1), 512, 0, stream>>>(
      Xb, QKVT, bq, bk, bv, Qb, M_TOK, 3072, HDIM, HDIM);

  attn_kernel<<<dim3(2048, 1, 1), 256, 0, stream>>>(Qb, Kb, Vtb, am, Po, Lp);
  attn_merge<<<dim3(SEQ / 64, BATCH * NHEAD), 256, 0, stream>>>(Po, Lp, Ab);

  gemm_bt<1><<<dim3(HDIM / 128, M_TOK / 128, 2), 256, 0, stream>>>(
      Ab, WoT, nullptr, nullptr, nullptr, Pw, M_TOK, HDIM, HDIM, 512);
  ln_sum<2, 1><<<M_TOK, 256, 0, stream>>>(Pw, bo, ln1g, ln1b, L1);

  gemm256<2><<<dim3(FFDIM / 256, M_TOK / 256, 1), 512, 0, stream>>>(
      L1, W1T, b1, nullptr, nullptr, F1, M_TOK, FFDIM, HDIM, HDIM);

  gemm256<1><<<dim3(HDIM / 256, M_TOK / 256, 4), 512, 0, stream>>>(
      F1, W2T, nullptr, nullptr, nullptr, Pf, M_TOK, HDIM, FFDIM, 1024);
  ln_sum<4, 0><<<M_TOK, 256, 0, stream>>>(Pf, b2, ln2g, ln2b, (float*)d_out);
}